// Round 9
// baseline (764.308 us; speedup 1.0000x reference)
//
#include <hip/hip_runtime.h>

// Problem constants
constexpr int NN  = 131072;   // nodes
constexpr int NE  = 2097152;  // edges
constexpr int HD  = 128;      // hidden
constexpr int NG  = 8192;     // graphs
constexpr int NA  = 28;       // atom types
constexpr int NL  = 4;        // layers

// CSR bucketing
constexpr int NB   = 256;     // buckets
constexpr int BSH  = 9;       // dst>>9 -> bucket (512 nodes/bucket)
constexpr int BNOD = 512;     // nodes per bucket
constexpr int CAP  = 10240;   // slots per bucket (mean 8192 + 22 sigma)

// ---------------- workspace layout (bytes) ----------------
constexpr size_t SZ_FB   = (size_t)NN * HD * 2;          // 32 MiB bf16 feature buf
constexpr size_t OFF_XB   = 0;
constexpr size_t OFF_YB   = OFF_XB + SZ_FB;
constexpr size_t OFF_PB   = OFF_YB + SZ_FB;              // P = H @ W2 (gather source)
constexpr size_t OFF_ESRC = OFF_PB + SZ_FB;
constexpr size_t OFF_DEG  = OFF_ESRC + (size_t)NE * 4;
constexpr size_t OFF_GCNT = OFF_DEG + (size_t)NN * 4;
constexpr size_t OFF_ROW  = OFF_GCNT + (size_t)NG * 4;
constexpr size_t OFF_IDEG = OFF_ROW + (size_t)NN * 4;
constexpr size_t OFF_IGC  = OFF_IDEG + (size_t)NN * 4;
constexpr size_t OFF_BSUM = OFF_IGC + (size_t)NG * 4;
constexpr size_t OFF_COFF = OFF_BSUM + 512;
constexpr size_t OFF_WC   = OFF_COFF + 512;
constexpr size_t OFF_WNT  = OFF_WC + 512;                // bf16 W transposed [L][128][256]
constexpr size_t OFF_EBUF = OFF_WNT + (size_t)NL * HD * 256 * 2;
constexpr size_t OFF_GCUR = OFF_EBUF + (size_t)NB * CAP * 4;
constexpr size_t OFF_WET  = OFF_GCUR + (size_t)NB * 4;   // bf16 W_emb^T [128][32]

// ---------------- bf16 helpers ----------------
__device__ __forceinline__ float blo(uint x) { return __uint_as_float(x << 16); }
__device__ __forceinline__ float bhi(uint x) { return __uint_as_float(x & 0xFFFF0000u); }
__device__ __forceinline__ unsigned short f2b(float f) {
  uint u = __float_as_uint(f);
  return (unsigned short)((u + 0x7FFFu + ((u >> 16) & 1u)) >> 16);
}
__device__ __forceinline__ uint pack2(float a, float b) {
  uint ua = __float_as_uint(a), ub = __float_as_uint(b);
  uint lo = (ua + 0x7FFFu + ((ua >> 16) & 1u)) >> 16;
  uint hi = (ub + 0x7FFFu + ((ub >> 16) & 1u)) & 0xFFFF0000u;
  return lo | hi;
}

typedef __attribute__((ext_vector_type(8))) short bf16x8;
typedef __attribute__((ext_vector_type(4))) float f32x4;

// ---------------- CSR build: bucketed ----------------
__global__ void k_binit(int* __restrict__ gcur) {
  int b = threadIdx.x;           // 256
  gcur[b] = b * CAP;
}

// partition edges into NB buckets by dst>>BSH; packed = (dst&511)<<17 | src
__global__ __launch_bounds__(256) void k_bin(const int* __restrict__ src,
                                             const int* __restrict__ dst,
                                             int* __restrict__ gcur,
                                             uint* __restrict__ ebuf) {
  __shared__ int cnt[NB];
  __shared__ int gbase[NB];
  int t = threadIdx.x;
  cnt[t] = 0;
  int es[16], ed[16];
  int base = blockIdx.x * 4096 + t;
#pragma unroll
  for (int j = 0; j < 16; j++) {
    es[j] = src[base + j * 256];
    ed[j] = dst[base + j * 256];
  }
  __syncthreads();
#pragma unroll
  for (int j = 0; j < 16; j++) atomicAdd(&cnt[ed[j] >> BSH], 1);
  __syncthreads();
  int c = cnt[t];
  if (c > 0) gbase[t] = atomicAdd(&gcur[t], c);
  cnt[t] = 0;
  __syncthreads();
#pragma unroll
  for (int j = 0; j < 16; j++) {
    int b = ed[j] >> BSH;
    int r = atomicAdd(&cnt[b], 1);
    ebuf[(size_t)gbase[b] + r] = ((uint)(ed[j] & (BNOD - 1)) << 17) | (uint)es[j];
  }
}

// per-bucket degree histogram (LDS), coalesced deg writes, no global atomics
__global__ __launch_bounds__(256) void k_deg(const int* __restrict__ gcur,
                                             const uint* __restrict__ ebuf,
                                             int* __restrict__ deg) {
  __shared__ int h[BNOD];
  int b = blockIdx.x, t = threadIdx.x;
  h[t] = 0; h[t + 256] = 0;
  int n = gcur[b] - b * CAP;
  __syncthreads();
  const uint* eb = ebuf + (size_t)b * CAP;
  for (int i = t; i < n; i += 256) atomicAdd(&h[eb[i] >> 17], 1);
  __syncthreads();
  deg[b * BNOD + t] = h[t];
  deg[b * BNOD + t + 256] = h[t + 256];
}

__global__ void k_scan1(const int* __restrict__ deg, int* __restrict__ bsum) {
  __shared__ int s[256];
  int b = blockIdx.x, t = threadIdx.x;
  const int4* p = (const int4*)(deg + (size_t)b * 1024);
  int4 v = p[t];
  s[t] = v.x + v.y + v.z + v.w;
  __syncthreads();
  for (int o = 128; o > 0; o >>= 1) {
    if (t < o) s[t] += s[t + o];
    __syncthreads();
  }
  if (t == 0) bsum[b] = s[0];
}

__global__ void k_scan2(const int* __restrict__ bsum, int* __restrict__ coff) {
  __shared__ int s[128];
  int t = threadIdx.x;
  int mine = bsum[t];
  s[t] = mine;
  __syncthreads();
  for (int o = 1; o < 128; o <<= 1) {
    int v = (t >= o) ? s[t - o] : 0;
    __syncthreads();
    s[t] += v;
    __syncthreads();
  }
  coff[t] = s[t] - mine;  // exclusive
}

__global__ void k_scan3(const int* __restrict__ deg, const int* __restrict__ coff,
                        int* __restrict__ row_start, float* __restrict__ inv_deg) {
  __shared__ int s[256];
  int b = blockIdx.x, t = threadIdx.x;
  int base = b * 1024 + t * 4;
  const int4* p = (const int4*)(deg + base);
  int4 d = *p;
  int lsum = d.x + d.y + d.z + d.w;
  s[t] = lsum;
  __syncthreads();
  for (int o = 1; o < 256; o <<= 1) {
    int v = (t >= o) ? s[t - o] : 0;
    __syncthreads();
    s[t] += v;
    __syncthreads();
  }
  int pre = coff[b] + s[t] - lsum;
  int r0 = pre, r1 = r0 + d.x, r2 = r1 + d.y, r3 = r2 + d.z;
  row_start[base] = r0;  row_start[base + 1] = r1;
  row_start[base + 2] = r2;  row_start[base + 3] = r3;
  inv_deg[base]     = 1.0f / fmaxf((float)d.x, 1.0f);
  inv_deg[base + 1] = 1.0f / fmaxf((float)d.y, 1.0f);
  inv_deg[base + 2] = 1.0f / fmaxf((float)d.z, 1.0f);
  inv_deg[base + 3] = 1.0f / fmaxf((float)d.w, 1.0f);
}

// per-bucket placement: LDS cursors, esrc writes land in a 32KB window
__global__ __launch_bounds__(256) void k_place2(const int* __restrict__ gcur,
                                                const uint* __restrict__ ebuf,
                                                const int* __restrict__ row_start,
                                                int* __restrict__ esrc) {
  __shared__ int cur[BNOD];
  int b = blockIdx.x, t = threadIdx.x;
  cur[t] = row_start[b * BNOD + t];
  cur[t + 256] = row_start[b * BNOD + t + 256];
  int n = gcur[b] - b * CAP;
  __syncthreads();
  const uint* eb = ebuf + (size_t)b * CAP;
  for (int i = t; i < n; i += 256) {
    uint p = eb[i];
    int r = atomicAdd(&cur[p >> 17], 1);
    esrc[r] = (int)(p & 0x1FFFFu);
  }
}

__global__ void k_ghist(const int* __restrict__ gid, int* __restrict__ gcnt) {
  int i = blockIdx.x * blockDim.x + threadIdx.x;
  if (i < NN) atomicAdd(&gcnt[gid[i]], 1);
}

__global__ void k_ginit(const int* __restrict__ gcnt, float* __restrict__ inv_gcnt,
                        float* __restrict__ out, const float* __restrict__ b_pred) {
  int g = blockIdx.x * blockDim.x + threadIdx.x;
  if (g < NG) {
    inv_gcnt[g] = 1.0f / fmaxf((float)gcnt[g], 1.0f);
    out[g] = b_pred[0];
  }
}

// ---------------- weight prep ----------------
// Wnt[l][c][k] = bf16(W_node[l][k][c])
__global__ void k_wprep(const float* __restrict__ Wn, unsigned short* __restrict__ Wnt) {
  int i = blockIdx.x * 256 + threadIdx.x;   // L*256*128 total
  int l = i >> 15;
  int k = (i >> 7) & 255;
  int c = i & 127;
  float v = Wn[((size_t)l * 256 + k) * HD + c];
  Wnt[((size_t)l * HD + c) * 256 + k] = f2b(v);
}

// Wet[c][k] = bf16(W_emb[k][c]), k padded 28->32 with zeros
__global__ void k_weprep(const float* __restrict__ We, unsigned short* __restrict__ Wet) {
  int i = blockIdx.x * 256 + threadIdx.x;   // 128*32 = 4096 total
  int col = i >> 5, k = i & 31;
  Wet[i] = (k < NA) ? f2b(We[(size_t)k * HD + col]) : (unsigned short)0;
}

// ---------------- embedding (MFMA): Xb = bf16(h @ W_emb) ----------------
// block: 64 rows x 128 cols, 4 waves 2x2; K=32 (padded from 28)
__global__ __launch_bounds__(256) void k_embed(const float* __restrict__ h,
                                               const unsigned short* __restrict__ Wet,
                                               unsigned short* __restrict__ Xb) {
  int t = threadIdx.x;
  int lane = t & 63, w = t >> 6;
  int wr = w >> 1, wc = w & 1;
  int row0 = blockIdx.x * 64 + wr * 32;
  int col0 = wc * 64;
  int fr = lane & 15;
  int fk = (lane >> 4) * 8;

  f32x4 acc[2][4] = {};
  bf16x8 a[2];
#pragma unroll
  for (int rt = 0; rt < 2; rt++) {
    int row = row0 + rt * 16 + fr;
    const float* hp = h + (size_t)row * NA + fk;
    float4 p = *(const float4*)hp;                    // k = fk..fk+3 (always < 28)
    float4 q = make_float4(0.f, 0.f, 0.f, 0.f);
    if (fk < 24) q = *(const float4*)(hp + 4);        // k = fk+4..fk+7; fk==24 -> pad 0
    a[rt][0] = (short)f2b(p.x); a[rt][1] = (short)f2b(p.y);
    a[rt][2] = (short)f2b(p.z); a[rt][3] = (short)f2b(p.w);
    a[rt][4] = (short)f2b(q.x); a[rt][5] = (short)f2b(q.y);
    a[rt][6] = (short)f2b(q.z); a[rt][7] = (short)f2b(q.w);
  }
#pragma unroll
  for (int ct = 0; ct < 4; ct++) {
    int col = col0 + ct * 16 + fr;
    bf16x8 b = *(const bf16x8*)(Wet + (size_t)col * 32 + fk);
#pragma unroll
    for (int rt = 0; rt < 2; rt++)
      acc[rt][ct] = __builtin_amdgcn_mfma_f32_16x16x32_bf16(a[rt], b, acc[rt][ct], 0, 0, 0);
  }
  int oc = lane & 15, orb = (lane >> 4) * 4;
#pragma unroll
  for (int rt = 0; rt < 2; rt++) {
#pragma unroll
    for (int ct = 0; ct < 4; ct++) {
      int col = col0 + ct * 16 + oc;
#pragma unroll
      for (int r = 0; r < 4; r++) {
        int row = row0 + rt * 16 + orb + r;
        Xb[(size_t)row * HD + col] = f2b(acc[rt][ct][r]);
      }
    }
  }
}

// ---------------- dual GEMM (MFMA, swapped operands): ----------------
// Qb = bf16(Hb @ W1 + bias), Pb = bf16(Hb @ W2); W = [W1; W2] (256 x 128).
// Lane owns one node (col=lane&15) and 4 consecutive channels -> uint2 stores.
__global__ __launch_bounds__(256) void k_pq(const unsigned short* __restrict__ Hb,
                                            unsigned short* __restrict__ Pb,
                                            unsigned short* __restrict__ Qb,
                                            const unsigned short* __restrict__ Wt,
                                            const float* __restrict__ bias) {
  int t = threadIdx.x;
  int lane = t & 63, w = t >> 6;
  int fr = lane & 15, fkg = lane >> 4;
  int node = blockIdx.x * 64 + w * 16 + fr;

  f32x4 accQ[8] = {}, accP[8] = {};
#pragma unroll
  for (int ks = 0; ks < 4; ks++) {
    bf16x8 aH = *(const bf16x8*)(Hb + (size_t)node * HD + ks * 32 + fkg * 8);
#pragma unroll
    for (int ct = 0; ct < 8; ct++) {
      const unsigned short* wrow = Wt + (size_t)(ct * 16 + fr) * 256 + ks * 32 + fkg * 8;
      bf16x8 b1 = *(const bf16x8*)wrow;           // W1: k in [0,128)
      bf16x8 b2 = *(const bf16x8*)(wrow + 128);   // W2: k in [128,256)
      accQ[ct] = __builtin_amdgcn_mfma_f32_16x16x32_bf16(b1, aH, accQ[ct], 0, 0, 0);
      accP[ct] = __builtin_amdgcn_mfma_f32_16x16x32_bf16(b2, aH, accP[ct], 0, 0, 0);
    }
  }
  // epilogue: lane -> node, channels c0..c0+3 per ct
#pragma unroll
  for (int ct = 0; ct < 8; ct++) {
    int c0 = ct * 16 + fkg * 4;
    float4 bv = *(const float4*)(bias + c0);
    uint2 q, p;
    q.x = pack2(accQ[ct][0] + bv.x, accQ[ct][1] + bv.y);
    q.y = pack2(accQ[ct][2] + bv.z, accQ[ct][3] + bv.w);
    p.x = pack2(accP[ct][0], accP[ct][1]);
    p.y = pack2(accP[ct][2], accP[ct][3]);
    *(uint2*)(Qb + (size_t)node * HD + c0) = q;
    *(uint2*)(Pb + (size_t)node * HD + c0) = p;
  }
}

// ---------------- gather + layer epilogue ----------------
// one wave per node; lane holds 2 cols (uint); 8 gather loads of P in flight.
// O[v] = relu(Q[v] + mean_{u->v} P[u]) * snorm[v] + Hres[v]
// last layer: no O write; readout dot + atomicAdd instead.
__global__ __launch_bounds__(256) void k_gapply(const uint* __restrict__ Pg,
                      const uint* __restrict__ Qg, const uint* __restrict__ Hres,
                      uint* __restrict__ Og,
                      const int* __restrict__ row_start, const int* __restrict__ deg,
                      const int* __restrict__ esrc, const float* __restrict__ inv_deg,
                      const float* __restrict__ snorm,
                      const float* __restrict__ wcv, const int* __restrict__ gid,
                      const float* __restrict__ inv_gcnt, float* __restrict__ out,
                      int last) {
  int v = blockIdx.x * 4 + (threadIdx.x >> 6);
  int lane = threadIdx.x & 63;
  int rs = __builtin_amdgcn_readfirstlane(row_start[v]);
  int d  = __builtin_amdgcn_readfirstlane(deg[v]);
  float s0 = 0.f, s1 = 0.f, t0 = 0.f, t1 = 0.f;
  float u0 = 0.f, u1 = 0.f, w0 = 0.f, w1 = 0.f;
  int e = 0;
  for (; e + 8 <= d; e += 8) {
    int i0 = esrc[rs + e];
    int i1 = esrc[rs + e + 1];
    int i2 = esrc[rs + e + 2];
    int i3 = esrc[rs + e + 3];
    int i4 = esrc[rs + e + 4];
    int i5 = esrc[rs + e + 5];
    int i6 = esrc[rs + e + 6];
    int i7 = esrc[rs + e + 7];
    uint x0 = Pg[(size_t)i0 * 64 + lane];
    uint x1 = Pg[(size_t)i1 * 64 + lane];
    uint x2 = Pg[(size_t)i2 * 64 + lane];
    uint x3 = Pg[(size_t)i3 * 64 + lane];
    uint x4 = Pg[(size_t)i4 * 64 + lane];
    uint x5 = Pg[(size_t)i5 * 64 + lane];
    uint x6 = Pg[(size_t)i6 * 64 + lane];
    uint x7 = Pg[(size_t)i7 * 64 + lane];
    s0 += blo(x0); s1 += bhi(x0);
    t0 += blo(x1); t1 += bhi(x1);
    u0 += blo(x2); u1 += bhi(x2);
    w0 += blo(x3); w1 += bhi(x3);
    s0 += blo(x4); s1 += bhi(x4);
    t0 += blo(x5); t1 += bhi(x5);
    u0 += blo(x6); u1 += bhi(x6);
    w0 += blo(x7); w1 += bhi(x7);
  }
  for (; e + 4 <= d; e += 4) {
    int i0 = esrc[rs + e];
    int i1 = esrc[rs + e + 1];
    int i2 = esrc[rs + e + 2];
    int i3 = esrc[rs + e + 3];
    uint x0 = Pg[(size_t)i0 * 64 + lane];
    uint x1 = Pg[(size_t)i1 * 64 + lane];
    uint x2 = Pg[(size_t)i2 * 64 + lane];
    uint x3 = Pg[(size_t)i3 * 64 + lane];
    s0 += blo(x0); s1 += bhi(x0);
    t0 += blo(x1); t1 += bhi(x1);
    u0 += blo(x2); u1 += bhi(x2);
    w0 += blo(x3); w1 += bhi(x3);
  }
  for (; e < d; e++) {
    uint x = Pg[(size_t)esrc[rs + e] * 64 + lane];
    s0 += blo(x); s1 += bhi(x);
  }
  float id = inv_deg[v];
  float m0 = ((s0 + t0) + (u0 + w0)) * id;
  float m1 = ((s1 + t1) + (u1 + w1)) * id;

  uint q  = Qg[(size_t)v * 64 + lane];
  uint hr = Hres[(size_t)v * 64 + lane];
  float sn = snorm[v];
  float o0 = fmaxf(blo(q) + m0, 0.f) * sn + blo(hr);
  float o1 = fmaxf(bhi(q) + m1, 0.f) * sn + bhi(hr);

  if (!last) {
    Og[(size_t)v * 64 + lane] = pack2(o0, o1);
  } else {
    float2 wv = *(const float2*)(wcv + lane * 2);
    float p = o0 * wv.x + o1 * wv.y;
#pragma unroll
    for (int o = 32; o > 0; o >>= 1) p += __shfl_down(p, o, 64);
    if (lane == 0) {
      int g = gid[v];
      atomicAdd(&out[g], p * inv_gcnt[g]);
    }
  }
}

// ---------------- readout weight combo ----------------
__global__ void k_wcombo(const float* __restrict__ W_ro, const float* __restrict__ W_pred,
                         float* __restrict__ wcv) {
  int i = threadIdx.x;  // 128
  float a = 0.f;
  for (int j = 0; j < HD; j++) a += W_ro[i * HD + j] * W_pred[j];
  wcv[i] = a;
}

// ---------------- launch ----------------
extern "C" void kernel_launch(void* const* d_in, const int* in_sizes, int n_in,
                              void* d_out, int out_size, void* d_ws, size_t ws_size,
                              hipStream_t stream) {
  const float* h      = (const float*)d_in[0];
  const float* snorm  = (const float*)d_in[1];
  const float* W_emb  = (const float*)d_in[2];
  const float* W_node = (const float*)d_in[3];
  const float* b_node = (const float*)d_in[4];
  const float* W_ro   = (const float*)d_in[5];
  const float* W_pred = (const float*)d_in[6];
  const float* b_pred = (const float*)d_in[7];
  const int*   src    = (const int*)d_in[8];
  const int*   dst    = (const int*)d_in[9];
  const int*   gid    = (const int*)d_in[10];
  float* out = (float*)d_out;

  char* ws = (char*)d_ws;
  unsigned short* Xb   = (unsigned short*)(ws + OFF_XB);
  unsigned short* Yb   = (unsigned short*)(ws + OFF_YB);
  unsigned short* Pb   = (unsigned short*)(ws + OFF_PB);
  int*   esrc     = (int*)(ws + OFF_ESRC);
  int*   deg      = (int*)(ws + OFF_DEG);
  int*   gcnt     = (int*)(ws + OFF_GCNT);
  int*   row_s    = (int*)(ws + OFF_ROW);
  float* inv_deg  = (float*)(ws + OFF_IDEG);
  float* inv_gcnt = (float*)(ws + OFF_IGC);
  int*   bsum     = (int*)(ws + OFF_BSUM);
  int*   coff     = (int*)(ws + OFF_COFF);
  float* wcv      = (float*)(ws + OFF_WC);
  unsigned short* Wnt = (unsigned short*)(ws + OFF_WNT);
  uint*  ebuf     = (uint*)(ws + OFF_EBUF);
  int*   gcur     = (int*)(ws + OFF_GCUR);
  unsigned short* Wet = (unsigned short*)(ws + OFF_WET);

  hipMemsetAsync(ws + OFF_GCNT, 0, (size_t)NG * 4, stream);

  k_binit<<<1, NB, 0, stream>>>(gcur);
  k_bin<<<NE / 4096, 256, 0, stream>>>(src, dst, gcur, ebuf);
  k_deg<<<NB, 256, 0, stream>>>(gcur, ebuf, deg);
  k_scan1<<<NN / 1024, 256, 0, stream>>>(deg, bsum);
  k_scan2<<<1, 128, 0, stream>>>(bsum, coff);
  k_scan3<<<NN / 1024, 256, 0, stream>>>(deg, coff, row_s, inv_deg);
  k_place2<<<NB, 256, 0, stream>>>(gcur, ebuf, row_s, esrc);
  k_ghist<<<NN / 256, 256, 0, stream>>>(gid, gcnt);
  k_ginit<<<NG / 256, 256, 0, stream>>>(gcnt, inv_gcnt, out, b_pred);
  k_wprep<<<(NL * 256 * HD) / 256, 256, 0, stream>>>(W_node, Wnt);
  k_weprep<<<(HD * 32) / 256, 256, 0, stream>>>(W_emb, Wet);
  k_wcombo<<<1, 128, 0, stream>>>(W_ro, W_pred, wcv);

  k_embed<<<NN / 64, 256, 0, stream>>>(h, Wet, Xb);

  for (int l = 0; l < NL; l++) {
    unsigned short* hb = (l & 1) ? Yb : Xb;   // layer input
    unsigned short* qo = (l & 1) ? Xb : Yb;   // Q buffer, overwritten in-place by O
    k_pq<<<NN / 64, 256, 0, stream>>>(hb, Pb, qo, Wnt + (size_t)l * HD * 256,
                                      b_node + (size_t)l * HD);
    k_gapply<<<NN / 4, 256, 0, stream>>>((const uint*)Pb, (const uint*)qo,
                                         (const uint*)hb, (uint*)qo,
                                         row_s, deg, esrc, inv_deg, snorm,
                                         wcv, gid, inv_gcnt, out, (l == NL - 1) ? 1 : 0);
  }
}

// Round 10
// 600.980 us; speedup vs baseline: 1.2718x; 1.2718x over previous
//
#include <hip/hip_runtime.h>

// Problem constants
constexpr int NN  = 131072;   // nodes
constexpr int NE  = 2097152;  // edges
constexpr int HD  = 128;      // hidden
constexpr int NG  = 8192;     // graphs
constexpr int NA  = 28;       // atom types
constexpr int NL  = 4;        // layers

// CSR bucketing
constexpr int NB   = 256;     // buckets
constexpr int BSH  = 9;       // dst>>9 -> bucket (512 nodes/bucket)
constexpr int BNOD = 512;     // nodes per bucket
constexpr int CAP  = 10240;   // slots per bucket (mean 8192 + 22 sigma)

// ---------------- workspace layout (bytes) ----------------
constexpr size_t SZ_FB   = (size_t)NN * HD * 2;          // 32 MiB bf16 feature buf
constexpr size_t OFF_XB   = 0;
constexpr size_t OFF_YB   = OFF_XB + SZ_FB;
constexpr size_t OFF_PB   = OFF_YB + SZ_FB;              // P = H @ W2, fp8 e4m3 (16 MiB)
constexpr size_t OFF_ESRC = OFF_PB + SZ_FB;
constexpr size_t OFF_DEG  = OFF_ESRC + (size_t)NE * 4;
constexpr size_t OFF_GCNT = OFF_DEG + (size_t)NN * 4;
constexpr size_t OFF_ROW  = OFF_GCNT + (size_t)NG * 4;
constexpr size_t OFF_IDEG = OFF_ROW + (size_t)NN * 4;
constexpr size_t OFF_IGC  = OFF_IDEG + (size_t)NN * 4;
constexpr size_t OFF_BSUM = OFF_IGC + (size_t)NG * 4;
constexpr size_t OFF_COFF = OFF_BSUM + 512;
constexpr size_t OFF_WC   = OFF_COFF + 512;
constexpr size_t OFF_WNT  = OFF_WC + 512;                // bf16 W transposed [L][128][256]
constexpr size_t OFF_EBUF = OFF_WNT + (size_t)NL * HD * 256 * 2;
constexpr size_t OFF_GCUR = OFF_EBUF + (size_t)NB * CAP * 4;
constexpr size_t OFF_WET  = OFF_GCUR + (size_t)NB * 4;   // bf16 W_emb^T [128][32]

// ---------------- bf16 / fp8 helpers ----------------
__device__ __forceinline__ float blo(uint x) { return __uint_as_float(x << 16); }
__device__ __forceinline__ float bhi(uint x) { return __uint_as_float(x & 0xFFFF0000u); }
__device__ __forceinline__ unsigned short f2b(float f) {
  uint u = __float_as_uint(f);
  return (unsigned short)((u + 0x7FFFu + ((u >> 16) & 1u)) >> 16);
}
__device__ __forceinline__ uint pack2(float a, float b) {
  uint ua = __float_as_uint(a), ub = __float_as_uint(b);
  uint lo = (ua + 0x7FFFu + ((ua >> 16) & 1u)) >> 16;
  uint hi = (ub + 0x7FFFu + ((ub >> 16) & 1u)) & 0xFFFF0000u;
  return lo | hi;
}

typedef __attribute__((ext_vector_type(8))) short bf16x8;
typedef __attribute__((ext_vector_type(4))) float f32x4;
typedef __attribute__((ext_vector_type(2))) float f32x2;

// pack 4 f32 -> 4 fp8 e4m3 in one uint (2 HW instrs)
__device__ __forceinline__ uint pk_fp8x4(float a, float b, float c, float d) {
  int p = __builtin_amdgcn_cvt_pk_fp8_f32(a, b, 0, false);
  p = __builtin_amdgcn_cvt_pk_fp8_f32(c, d, p, true);
  return (uint)p;
}

// ---------------- CSR build: bucketed ----------------
__global__ void k_binit(int* __restrict__ gcur) {
  int b = threadIdx.x;           // 256
  gcur[b] = b * CAP;
}

// partition edges into NB buckets by dst>>BSH; packed = (dst&511)<<17 | src
__global__ __launch_bounds__(256) void k_bin(const int* __restrict__ src,
                                             const int* __restrict__ dst,
                                             int* __restrict__ gcur,
                                             uint* __restrict__ ebuf) {
  __shared__ int cnt[NB];
  __shared__ int gbase[NB];
  int t = threadIdx.x;
  cnt[t] = 0;
  int es[16], ed[16];
  int base = blockIdx.x * 4096 + t;
#pragma unroll
  for (int j = 0; j < 16; j++) {
    es[j] = src[base + j * 256];
    ed[j] = dst[base + j * 256];
  }
  __syncthreads();
#pragma unroll
  for (int j = 0; j < 16; j++) atomicAdd(&cnt[ed[j] >> BSH], 1);
  __syncthreads();
  int c = cnt[t];
  if (c > 0) gbase[t] = atomicAdd(&gcur[t], c);
  cnt[t] = 0;
  __syncthreads();
#pragma unroll
  for (int j = 0; j < 16; j++) {
    int b = ed[j] >> BSH;
    int r = atomicAdd(&cnt[b], 1);
    ebuf[(size_t)gbase[b] + r] = ((uint)(ed[j] & (BNOD - 1)) << 17) | (uint)es[j];
  }
}

// per-bucket degree histogram (LDS), coalesced deg writes, no global atomics
__global__ __launch_bounds__(256) void k_deg(const int* __restrict__ gcur,
                                             const uint* __restrict__ ebuf,
                                             int* __restrict__ deg) {
  __shared__ int h[BNOD];
  int b = blockIdx.x, t = threadIdx.x;
  h[t] = 0; h[t + 256] = 0;
  int n = gcur[b] - b * CAP;
  __syncthreads();
  const uint* eb = ebuf + (size_t)b * CAP;
  for (int i = t; i < n; i += 256) atomicAdd(&h[eb[i] >> 17], 1);
  __syncthreads();
  deg[b * BNOD + t] = h[t];
  deg[b * BNOD + t + 256] = h[t + 256];
}

__global__ void k_scan1(const int* __restrict__ deg, int* __restrict__ bsum) {
  __shared__ int s[256];
  int b = blockIdx.x, t = threadIdx.x;
  const int4* p = (const int4*)(deg + (size_t)b * 1024);
  int4 v = p[t];
  s[t] = v.x + v.y + v.z + v.w;
  __syncthreads();
  for (int o = 128; o > 0; o >>= 1) {
    if (t < o) s[t] += s[t + o];
    __syncthreads();
  }
  if (t == 0) bsum[b] = s[0];
}

__global__ void k_scan2(const int* __restrict__ bsum, int* __restrict__ coff) {
  __shared__ int s[128];
  int t = threadIdx.x;
  int mine = bsum[t];
  s[t] = mine;
  __syncthreads();
  for (int o = 1; o < 128; o <<= 1) {
    int v = (t >= o) ? s[t - o] : 0;
    __syncthreads();
    s[t] += v;
    __syncthreads();
  }
  coff[t] = s[t] - mine;  // exclusive
}

__global__ void k_scan3(const int* __restrict__ deg, const int* __restrict__ coff,
                        int* __restrict__ row_start, float* __restrict__ inv_deg) {
  __shared__ int s[256];
  int b = blockIdx.x, t = threadIdx.x;
  int base = b * 1024 + t * 4;
  const int4* p = (const int4*)(deg + base);
  int4 d = *p;
  int lsum = d.x + d.y + d.z + d.w;
  s[t] = lsum;
  __syncthreads();
  for (int o = 1; o < 256; o <<= 1) {
    int v = (t >= o) ? s[t - o] : 0;
    __syncthreads();
    s[t] += v;
    __syncthreads();
  }
  int pre = coff[b] + s[t] - lsum;
  int r0 = pre, r1 = r0 + d.x, r2 = r1 + d.y, r3 = r2 + d.z;
  row_start[base] = r0;  row_start[base + 1] = r1;
  row_start[base + 2] = r2;  row_start[base + 3] = r3;
  inv_deg[base]     = 1.0f / fmaxf((float)d.x, 1.0f);
  inv_deg[base + 1] = 1.0f / fmaxf((float)d.y, 1.0f);
  inv_deg[base + 2] = 1.0f / fmaxf((float)d.z, 1.0f);
  inv_deg[base + 3] = 1.0f / fmaxf((float)d.w, 1.0f);
}

// per-bucket placement: LDS cursors, esrc writes land in a 32KB window
__global__ __launch_bounds__(256) void k_place2(const int* __restrict__ gcur,
                                                const uint* __restrict__ ebuf,
                                                const int* __restrict__ row_start,
                                                int* __restrict__ esrc) {
  __shared__ int cur[BNOD];
  int b = blockIdx.x, t = threadIdx.x;
  cur[t] = row_start[b * BNOD + t];
  cur[t + 256] = row_start[b * BNOD + t + 256];
  int n = gcur[b] - b * CAP;
  __syncthreads();
  const uint* eb = ebuf + (size_t)b * CAP;
  for (int i = t; i < n; i += 256) {
    uint p = eb[i];
    int r = atomicAdd(&cur[p >> 17], 1);
    esrc[r] = (int)(p & 0x1FFFFu);
  }
}

__global__ void k_ghist(const int* __restrict__ gid, int* __restrict__ gcnt) {
  int i = blockIdx.x * blockDim.x + threadIdx.x;
  if (i < NN) atomicAdd(&gcnt[gid[i]], 1);
}

__global__ void k_ginit(const int* __restrict__ gcnt, float* __restrict__ inv_gcnt,
                        float* __restrict__ out, const float* __restrict__ b_pred) {
  int g = blockIdx.x * blockDim.x + threadIdx.x;
  if (g < NG) {
    inv_gcnt[g] = 1.0f / fmaxf((float)gcnt[g], 1.0f);
    out[g] = b_pred[0];
  }
}

// ---------------- weight prep ----------------
// Wnt[l][c][k] = bf16(W_node[l][k][c])
__global__ void k_wprep(const float* __restrict__ Wn, unsigned short* __restrict__ Wnt) {
  int i = blockIdx.x * 256 + threadIdx.x;   // L*256*128 total
  int l = i >> 15;
  int k = (i >> 7) & 255;
  int c = i & 127;
  float v = Wn[((size_t)l * 256 + k) * HD + c];
  Wnt[((size_t)l * HD + c) * 256 + k] = f2b(v);
}

// Wet[c][k] = bf16(W_emb[k][c]), k padded 28->32 with zeros
__global__ void k_weprep(const float* __restrict__ We, unsigned short* __restrict__ Wet) {
  int i = blockIdx.x * 256 + threadIdx.x;   // 128*32 = 4096 total
  int col = i >> 5, k = i & 31;
  Wet[i] = (k < NA) ? f2b(We[(size_t)k * HD + col]) : (unsigned short)0;
}

// ---------------- embedding (MFMA): Xb = bf16(h @ W_emb) ----------------
// block: 64 rows x 128 cols, 4 waves 2x2; K=32 (padded from 28)
__global__ __launch_bounds__(256) void k_embed(const float* __restrict__ h,
                                               const unsigned short* __restrict__ Wet,
                                               unsigned short* __restrict__ Xb) {
  int t = threadIdx.x;
  int lane = t & 63, w = t >> 6;
  int wr = w >> 1, wc = w & 1;
  int row0 = blockIdx.x * 64 + wr * 32;
  int col0 = wc * 64;
  int fr = lane & 15;
  int fk = (lane >> 4) * 8;

  f32x4 acc[2][4] = {};
  bf16x8 a[2];
#pragma unroll
  for (int rt = 0; rt < 2; rt++) {
    int row = row0 + rt * 16 + fr;
    const float* hp = h + (size_t)row * NA + fk;
    float4 p = *(const float4*)hp;                    // k = fk..fk+3 (always < 28)
    float4 q = make_float4(0.f, 0.f, 0.f, 0.f);
    if (fk < 24) q = *(const float4*)(hp + 4);        // k = fk+4..fk+7; fk==24 -> pad 0
    a[rt][0] = (short)f2b(p.x); a[rt][1] = (short)f2b(p.y);
    a[rt][2] = (short)f2b(p.z); a[rt][3] = (short)f2b(p.w);
    a[rt][4] = (short)f2b(q.x); a[rt][5] = (short)f2b(q.y);
    a[rt][6] = (short)f2b(q.z); a[rt][7] = (short)f2b(q.w);
  }
#pragma unroll
  for (int ct = 0; ct < 4; ct++) {
    int col = col0 + ct * 16 + fr;
    bf16x8 b = *(const bf16x8*)(Wet + (size_t)col * 32 + fk);
#pragma unroll
    for (int rt = 0; rt < 2; rt++)
      acc[rt][ct] = __builtin_amdgcn_mfma_f32_16x16x32_bf16(a[rt], b, acc[rt][ct], 0, 0, 0);
  }
  int oc = lane & 15, orb = (lane >> 4) * 4;
#pragma unroll
  for (int rt = 0; rt < 2; rt++) {
#pragma unroll
    for (int ct = 0; ct < 4; ct++) {
      int col = col0 + ct * 16 + oc;
#pragma unroll
      for (int r = 0; r < 4; r++) {
        int row = row0 + rt * 16 + orb + r;
        Xb[(size_t)row * HD + col] = f2b(acc[rt][ct][r]);
      }
    }
  }
}

// ---------------- dual GEMM (MFMA, swapped operands): ----------------
// Qb = bf16(Hb @ W1 + bias), Pb8 = fp8(Hb @ W2); W = [W1; W2] (256 x 128).
// wave = 32 nodes (2 A-frag tiles, B reused x2) x 64 cols; block = 64 nodes x 128.
__global__ __launch_bounds__(256) void k_pq(const unsigned short* __restrict__ Hb,
                                            uint* __restrict__ Pb8,
                                            unsigned short* __restrict__ Qb,
                                            const unsigned short* __restrict__ Wt,
                                            const float* __restrict__ bias) {
  int t = threadIdx.x;
  int lane = t & 63, w = t >> 6;
  int ng = w >> 1, cg = w & 1;
  int fr = lane & 15, fkg = lane >> 4;
  int n0 = blockIdx.x * 64 + ng * 32;

  f32x4 accQ[2][4] = {}, accP[2][4] = {};
#pragma unroll
  for (int ks = 0; ks < 4; ks++) {
    bf16x8 aH[2];
#pragma unroll
    for (int nt = 0; nt < 2; nt++)
      aH[nt] = *(const bf16x8*)(Hb + (size_t)(n0 + nt * 16 + fr) * HD + ks * 32 + fkg * 8);
#pragma unroll
    for (int ct = 0; ct < 4; ct++) {
      const unsigned short* wrow =
          Wt + (size_t)(cg * 64 + ct * 16 + fr) * 256 + ks * 32 + fkg * 8;
      bf16x8 b1 = *(const bf16x8*)wrow;           // W1: k in [0,128)
      bf16x8 b2 = *(const bf16x8*)(wrow + 128);   // W2: k in [128,256)
#pragma unroll
      for (int nt = 0; nt < 2; nt++) {
        accQ[nt][ct] = __builtin_amdgcn_mfma_f32_16x16x32_bf16(b1, aH[nt], accQ[nt][ct], 0, 0, 0);
        accP[nt][ct] = __builtin_amdgcn_mfma_f32_16x16x32_bf16(b2, aH[nt], accP[nt][ct], 0, 0, 0);
      }
    }
  }
  // epilogue: lane -> node = n0+nt*16+fr, channels c0..c0+3
#pragma unroll
  for (int nt = 0; nt < 2; nt++) {
    int node = n0 + nt * 16 + fr;
#pragma unroll
    for (int ct = 0; ct < 4; ct++) {
      int c0 = cg * 64 + ct * 16 + fkg * 4;
      float4 bv = *(const float4*)(bias + c0);
      uint2 q;
      q.x = pack2(accQ[nt][ct][0] + bv.x, accQ[nt][ct][1] + bv.y);
      q.y = pack2(accQ[nt][ct][2] + bv.z, accQ[nt][ct][3] + bv.w);
      *(uint2*)(Qb + (size_t)node * HD + c0) = q;
      Pb8[(size_t)node * 32 + (c0 >> 2)] =
          pk_fp8x4(accP[nt][ct][0], accP[nt][ct][1], accP[nt][ct][2], accP[nt][ct][3]);
    }
  }
}

// ---------------- gather (fp8 P) + layer epilogue ----------------
// one wave per node; 32 lanes cover the 128B fp8 row (uint = 4 cols/lane);
// 2 edges per load via half-select; 8 loads (16 edges) in flight.
// O[v] = relu(Q[v] + mean_{u->v} P[u]) * snorm[v] + Hres[v]; last layer: readout.
__global__ __launch_bounds__(256) void k_gapply(const uint* __restrict__ Pg,
                      const uint2* __restrict__ Qg, const uint2* __restrict__ Hres,
                      uint2* __restrict__ Og,
                      const int* __restrict__ row_start, const int* __restrict__ deg,
                      const int* __restrict__ esrc, const float* __restrict__ inv_deg,
                      const float* __restrict__ snorm,
                      const float* __restrict__ wcv, const int* __restrict__ gid,
                      const float* __restrict__ inv_gcnt, float* __restrict__ out,
                      int last) {
  int v = blockIdx.x * 4 + (threadIdx.x >> 6);
  int lane = threadIdx.x & 63;
  int half = lane >> 5;
  int cl = lane & 31;                       // cols 4cl .. 4cl+3
  int rs = __builtin_amdgcn_readfirstlane(row_start[v]);
  int d  = __builtin_amdgcn_readfirstlane(deg[v]);
  float a0 = 0.f, a1 = 0.f, a2 = 0.f, a3 = 0.f;
  float b0 = 0.f, b1 = 0.f, b2 = 0.f, b3 = 0.f;
  int e = 0;
  for (; e + 16 <= d; e += 16) {
    uint x[8];
#pragma unroll
    for (int j = 0; j < 8; j++) {
      int ea = esrc[rs + e + 2 * j];        // scalar loads (uniform addr)
      int eb = esrc[rs + e + 2 * j + 1];
      int idx = half ? eb : ea;
      x[j] = Pg[(size_t)idx * 32 + cl];
    }
#pragma unroll
    for (int j = 0; j < 8; j++) {
      f32x2 lo = __builtin_amdgcn_cvt_pk_f32_fp8((int)x[j], false);
      f32x2 hi = __builtin_amdgcn_cvt_pk_f32_fp8((int)x[j], true);
      if (j & 1) { b0 += lo[0]; b1 += lo[1]; b2 += hi[0]; b3 += hi[1]; }
      else       { a0 += lo[0]; a1 += lo[1]; a2 += hi[0]; a3 += hi[1]; }
    }
  }
  for (; e + 2 <= d; e += 2) {
    int ea = esrc[rs + e], eb = esrc[rs + e + 1];
    int idx = half ? eb : ea;
    uint x = Pg[(size_t)idx * 32 + cl];
    f32x2 lo = __builtin_amdgcn_cvt_pk_f32_fp8((int)x, false);
    f32x2 hi = __builtin_amdgcn_cvt_pk_f32_fp8((int)x, true);
    b0 += lo[0]; b1 += lo[1]; b2 += hi[0]; b3 += hi[1];
  }
  if (e < d) {
    uint x = Pg[(size_t)esrc[rs + e] * 32 + cl];
    f32x2 lo = __builtin_amdgcn_cvt_pk_f32_fp8((int)x, false);
    f32x2 hi = __builtin_amdgcn_cvt_pk_f32_fp8((int)x, true);
    if (half == 0) { a0 += lo[0]; a1 += lo[1]; a2 += hi[0]; a3 += hi[1]; }
  }
  a0 += b0; a1 += b1; a2 += b2; a3 += b3;
  a0 += __shfl_xor(a0, 32, 64);
  a1 += __shfl_xor(a1, 32, 64);
  a2 += __shfl_xor(a2, 32, 64);
  a3 += __shfl_xor(a3, 32, 64);

  if (half == 0) {
    float id = inv_deg[v];
    uint2 q  = Qg[(size_t)v * 32 + cl];
    uint2 hr = Hres[(size_t)v * 32 + cl];
    float sn = snorm[v];
    float o0 = fmaxf(blo(q.x) + a0 * id, 0.f) * sn + blo(hr.x);
    float o1 = fmaxf(bhi(q.x) + a1 * id, 0.f) * sn + bhi(hr.x);
    float o2 = fmaxf(blo(q.y) + a2 * id, 0.f) * sn + blo(hr.y);
    float o3 = fmaxf(bhi(q.y) + a3 * id, 0.f) * sn + bhi(hr.y);
    if (!last) {
      uint2 o;
      o.x = pack2(o0, o1);
      o.y = pack2(o2, o3);
      Og[(size_t)v * 32 + cl] = o;
    } else {
      float4 wv = *(const float4*)(wcv + 4 * cl);
      float p = o0 * wv.x + o1 * wv.y + o2 * wv.z + o3 * wv.w;
#pragma unroll
      for (int o = 16; o > 0; o >>= 1) p += __shfl_xor(p, o, 64);
      if (cl == 0) {
        int g = gid[v];
        atomicAdd(&out[g], p * inv_gcnt[g]);
      }
    }
  }
}

// ---------------- readout weight combo ----------------
__global__ void k_wcombo(const float* __restrict__ W_ro, const float* __restrict__ W_pred,
                         float* __restrict__ wcv) {
  int i = threadIdx.x;  // 128
  float a = 0.f;
  for (int j = 0; j < HD; j++) a += W_ro[i * HD + j] * W_pred[j];
  wcv[i] = a;
}

// ---------------- launch ----------------
extern "C" void kernel_launch(void* const* d_in, const int* in_sizes, int n_in,
                              void* d_out, int out_size, void* d_ws, size_t ws_size,
                              hipStream_t stream) {
  const float* h      = (const float*)d_in[0];
  const float* snorm  = (const float*)d_in[1];
  const float* W_emb  = (const float*)d_in[2];
  const float* W_node = (const float*)d_in[3];
  const float* b_node = (const float*)d_in[4];
  const float* W_ro   = (const float*)d_in[5];
  const float* W_pred = (const float*)d_in[6];
  const float* b_pred = (const float*)d_in[7];
  const int*   src    = (const int*)d_in[8];
  const int*   dst    = (const int*)d_in[9];
  const int*   gid    = (const int*)d_in[10];
  float* out = (float*)d_out;

  char* ws = (char*)d_ws;
  unsigned short* Xb   = (unsigned short*)(ws + OFF_XB);
  unsigned short* Yb   = (unsigned short*)(ws + OFF_YB);
  uint*  Pb8      = (uint*)(ws + OFF_PB);
  int*   esrc     = (int*)(ws + OFF_ESRC);
  int*   deg      = (int*)(ws + OFF_DEG);
  int*   gcnt     = (int*)(ws + OFF_GCNT);
  int*   row_s    = (int*)(ws + OFF_ROW);
  float* inv_deg  = (float*)(ws + OFF_IDEG);
  float* inv_gcnt = (float*)(ws + OFF_IGC);
  int*   bsum     = (int*)(ws + OFF_BSUM);
  int*   coff     = (int*)(ws + OFF_COFF);
  float* wcv      = (float*)(ws + OFF_WC);
  unsigned short* Wnt = (unsigned short*)(ws + OFF_WNT);
  uint*  ebuf     = (uint*)(ws + OFF_EBUF);
  int*   gcur     = (int*)(ws + OFF_GCUR);
  unsigned short* Wet = (unsigned short*)(ws + OFF_WET);

  hipMemsetAsync(ws + OFF_GCNT, 0, (size_t)NG * 4, stream);

  k_binit<<<1, NB, 0, stream>>>(gcur);
  k_bin<<<NE / 4096, 256, 0, stream>>>(src, dst, gcur, ebuf);
  k_deg<<<NB, 256, 0, stream>>>(gcur, ebuf, deg);
  k_scan1<<<NN / 1024, 256, 0, stream>>>(deg, bsum);
  k_scan2<<<1, 128, 0, stream>>>(bsum, coff);
  k_scan3<<<NN / 1024, 256, 0, stream>>>(deg, coff, row_s, inv_deg);
  k_place2<<<NB, 256, 0, stream>>>(gcur, ebuf, row_s, esrc);
  k_ghist<<<NN / 256, 256, 0, stream>>>(gid, gcnt);
  k_ginit<<<NG / 256, 256, 0, stream>>>(gcnt, inv_gcnt, out, b_pred);
  k_wprep<<<(NL * 256 * HD) / 256, 256, 0, stream>>>(W_node, Wnt);
  k_weprep<<<(HD * 32) / 256, 256, 0, stream>>>(W_emb, Wet);
  k_wcombo<<<1, 128, 0, stream>>>(W_ro, W_pred, wcv);

  k_embed<<<NN / 64, 256, 0, stream>>>(h, Wet, Xb);

  for (int l = 0; l < NL; l++) {
    unsigned short* hb = (l & 1) ? Yb : Xb;   // layer input
    unsigned short* qo = (l & 1) ? Xb : Yb;   // Q buffer, overwritten in-place by O
    k_pq<<<NN / 64, 256, 0, stream>>>(hb, Pb8, qo, Wnt + (size_t)l * HD * 256,
                                      b_node + (size_t)l * HD);
    k_gapply<<<NN / 4, 256, 0, stream>>>(Pb8, (const uint2*)qo,
                                         (const uint2*)hb, (uint2*)qo,
                                         row_s, deg, esrc, inv_deg, snorm,
                                         wcv, gid, inv_gcnt, out, (l == NL - 1) ? 1 : 0);
  }
}

// Round 11
// 587.331 us; speedup vs baseline: 1.3013x; 1.0232x over previous
//
#include <hip/hip_runtime.h>

// Problem constants
constexpr int NN  = 131072;   // nodes
constexpr int NE  = 2097152;  // edges
constexpr int HD  = 128;      // hidden
constexpr int NG  = 8192;     // graphs
constexpr int NA  = 28;       // atom types
constexpr int NL  = 4;        // layers

// CSR bucketing
constexpr int NB   = 256;     // buckets
constexpr int BSH  = 9;       // dst>>9 -> bucket (512 nodes/bucket)
constexpr int BNOD = 512;     // nodes per bucket
constexpr int CAP  = 10240;   // slots per bucket (mean 8192 + 22 sigma)

// ---------------- workspace layout (bytes) ----------------
constexpr size_t SZ_FB   = (size_t)NN * HD * 2;          // 32 MiB bf16 feature buf
constexpr size_t OFF_XB   = 0;
constexpr size_t OFF_YB   = OFF_XB + SZ_FB;
constexpr size_t OFF_PB   = OFF_YB + SZ_FB;              // P = H @ W2, fp8 e4m3 (16 MiB)
constexpr size_t OFF_ESRC = OFF_PB + SZ_FB;
constexpr size_t OFF_DEG  = OFF_ESRC + (size_t)NE * 4;
constexpr size_t OFF_GCNT = OFF_DEG + (size_t)NN * 4;
constexpr size_t OFF_ROW  = OFF_GCNT + (size_t)NG * 4;
constexpr size_t OFF_IDEG = OFF_ROW + (size_t)NN * 4;
constexpr size_t OFF_IGC  = OFF_IDEG + (size_t)NN * 4;
constexpr size_t OFF_BSUM = OFF_IGC + (size_t)NG * 4;
constexpr size_t OFF_COFF = OFF_BSUM + 512;
constexpr size_t OFF_WC   = OFF_COFF + 512;
constexpr size_t OFF_WNT  = OFF_WC + 512;                // bf16 W transposed [L][128][256]
constexpr size_t OFF_EBUF = OFF_WNT + (size_t)NL * HD * 256 * 2;
constexpr size_t OFF_GCUR = OFF_EBUF + (size_t)NB * CAP * 4;
constexpr size_t OFF_WET  = OFF_GCUR + (size_t)NB * 4;   // bf16 W_emb^T [128][32]

// ---------------- bf16 / fp8 helpers ----------------
__device__ __forceinline__ float blo(uint x) { return __uint_as_float(x << 16); }
__device__ __forceinline__ float bhi(uint x) { return __uint_as_float(x & 0xFFFF0000u); }
__device__ __forceinline__ unsigned short f2b(float f) {
  uint u = __float_as_uint(f);
  return (unsigned short)((u + 0x7FFFu + ((u >> 16) & 1u)) >> 16);
}
__device__ __forceinline__ uint pack2(float a, float b) {
  uint ua = __float_as_uint(a), ub = __float_as_uint(b);
  uint lo = (ua + 0x7FFFu + ((ua >> 16) & 1u)) >> 16;
  uint hi = (ub + 0x7FFFu + ((ub >> 16) & 1u)) & 0xFFFF0000u;
  return lo | hi;
}

typedef __attribute__((ext_vector_type(8))) short bf16x8;
typedef __attribute__((ext_vector_type(4))) float f32x4;
typedef __attribute__((ext_vector_type(2))) float f32x2;

// pack 4 f32 -> 4 fp8 e4m3 in one uint (2 HW instrs)
__device__ __forceinline__ uint pk_fp8x4(float a, float b, float c, float d) {
  int p = __builtin_amdgcn_cvt_pk_fp8_f32(a, b, 0, false);
  p = __builtin_amdgcn_cvt_pk_fp8_f32(c, d, p, true);
  return (uint)p;
}

// ---------------- CSR build: bucketed ----------------
__global__ void k_binit(int* __restrict__ gcur) {
  int b = threadIdx.x;           // 256
  gcur[b] = b * CAP;
}

// partition edges into NB buckets by dst>>BSH; packed = (dst&511)<<17 | src
__global__ __launch_bounds__(256) void k_bin(const int* __restrict__ src,
                                             const int* __restrict__ dst,
                                             int* __restrict__ gcur,
                                             uint* __restrict__ ebuf) {
  __shared__ int cnt[NB];
  __shared__ int gbase[NB];
  int t = threadIdx.x;
  cnt[t] = 0;
  int es[16], ed[16];
  int base = blockIdx.x * 4096 + t;
#pragma unroll
  for (int j = 0; j < 16; j++) {
    es[j] = src[base + j * 256];
    ed[j] = dst[base + j * 256];
  }
  __syncthreads();
#pragma unroll
  for (int j = 0; j < 16; j++) atomicAdd(&cnt[ed[j] >> BSH], 1);
  __syncthreads();
  int c = cnt[t];
  if (c > 0) gbase[t] = atomicAdd(&gcur[t], c);
  cnt[t] = 0;
  __syncthreads();
#pragma unroll
  for (int j = 0; j < 16; j++) {
    int b = ed[j] >> BSH;
    int r = atomicAdd(&cnt[b], 1);
    ebuf[(size_t)gbase[b] + r] = ((uint)(ed[j] & (BNOD - 1)) << 17) | (uint)es[j];
  }
}

// per-bucket degree histogram (LDS), coalesced deg writes, no global atomics
__global__ __launch_bounds__(256) void k_deg(const int* __restrict__ gcur,
                                             const uint* __restrict__ ebuf,
                                             int* __restrict__ deg) {
  __shared__ int h[BNOD];
  int b = blockIdx.x, t = threadIdx.x;
  h[t] = 0; h[t + 256] = 0;
  int n = gcur[b] - b * CAP;
  __syncthreads();
  const uint* eb = ebuf + (size_t)b * CAP;
  for (int i = t; i < n; i += 256) atomicAdd(&h[eb[i] >> 17], 1);
  __syncthreads();
  deg[b * BNOD + t] = h[t];
  deg[b * BNOD + t + 256] = h[t + 256];
}

__global__ void k_scan1(const int* __restrict__ deg, int* __restrict__ bsum) {
  __shared__ int s[256];
  int b = blockIdx.x, t = threadIdx.x;
  const int4* p = (const int4*)(deg + (size_t)b * 1024);
  int4 v = p[t];
  s[t] = v.x + v.y + v.z + v.w;
  __syncthreads();
  for (int o = 128; o > 0; o >>= 1) {
    if (t < o) s[t] += s[t + o];
    __syncthreads();
  }
  if (t == 0) bsum[b] = s[0];
}

__global__ void k_scan2(const int* __restrict__ bsum, int* __restrict__ coff) {
  __shared__ int s[128];
  int t = threadIdx.x;
  int mine = bsum[t];
  s[t] = mine;
  __syncthreads();
  for (int o = 1; o < 128; o <<= 1) {
    int v = (t >= o) ? s[t - o] : 0;
    __syncthreads();
    s[t] += v;
    __syncthreads();
  }
  coff[t] = s[t] - mine;  // exclusive
}

__global__ void k_scan3(const int* __restrict__ deg, const int* __restrict__ coff,
                        int* __restrict__ row_start, float* __restrict__ inv_deg) {
  __shared__ int s[256];
  int b = blockIdx.x, t = threadIdx.x;
  int base = b * 1024 + t * 4;
  const int4* p = (const int4*)(deg + base);
  int4 d = *p;
  int lsum = d.x + d.y + d.z + d.w;
  s[t] = lsum;
  __syncthreads();
  for (int o = 1; o < 256; o <<= 1) {
    int v = (t >= o) ? s[t - o] : 0;
    __syncthreads();
    s[t] += v;
    __syncthreads();
  }
  int pre = coff[b] + s[t] - lsum;
  int r0 = pre, r1 = r0 + d.x, r2 = r1 + d.y, r3 = r2 + d.z;
  row_start[base] = r0;  row_start[base + 1] = r1;
  row_start[base + 2] = r2;  row_start[base + 3] = r3;
  inv_deg[base]     = 1.0f / fmaxf((float)d.x, 1.0f);
  inv_deg[base + 1] = 1.0f / fmaxf((float)d.y, 1.0f);
  inv_deg[base + 2] = 1.0f / fmaxf((float)d.z, 1.0f);
  inv_deg[base + 3] = 1.0f / fmaxf((float)d.w, 1.0f);
}

// per-bucket placement: LDS cursors, esrc writes land in a 32KB window
__global__ __launch_bounds__(256) void k_place2(const int* __restrict__ gcur,
                                                const uint* __restrict__ ebuf,
                                                const int* __restrict__ row_start,
                                                int* __restrict__ esrc) {
  __shared__ int cur[BNOD];
  int b = blockIdx.x, t = threadIdx.x;
  cur[t] = row_start[b * BNOD + t];
  cur[t + 256] = row_start[b * BNOD + t + 256];
  int n = gcur[b] - b * CAP;
  __syncthreads();
  const uint* eb = ebuf + (size_t)b * CAP;
  for (int i = t; i < n; i += 256) {
    uint p = eb[i];
    int r = atomicAdd(&cur[p >> 17], 1);
    esrc[r] = (int)(p & 0x1FFFFu);
  }
}

__global__ void k_ghist(const int* __restrict__ gid, int* __restrict__ gcnt) {
  int i = blockIdx.x * blockDim.x + threadIdx.x;
  if (i < NN) atomicAdd(&gcnt[gid[i]], 1);
}

__global__ void k_ginit(const int* __restrict__ gcnt, float* __restrict__ inv_gcnt,
                        float* __restrict__ out, const float* __restrict__ b_pred) {
  int g = blockIdx.x * blockDim.x + threadIdx.x;
  if (g < NG) {
    inv_gcnt[g] = 1.0f / fmaxf((float)gcnt[g], 1.0f);
    out[g] = b_pred[0];
  }
}

// ---------------- weight prep ----------------
// Wnt[l][c][k] = bf16(W_node[l][k][c])
__global__ void k_wprep(const float* __restrict__ Wn, unsigned short* __restrict__ Wnt) {
  int i = blockIdx.x * 256 + threadIdx.x;   // L*256*128 total
  int l = i >> 15;
  int k = (i >> 7) & 255;
  int c = i & 127;
  float v = Wn[((size_t)l * 256 + k) * HD + c];
  Wnt[((size_t)l * HD + c) * 256 + k] = f2b(v);
}

// Wet[c][k] = bf16(W_emb[k][c]), k padded 28->32 with zeros
__global__ void k_weprep(const float* __restrict__ We, unsigned short* __restrict__ Wet) {
  int i = blockIdx.x * 256 + threadIdx.x;   // 128*32 = 4096 total
  int col = i >> 5, k = i & 31;
  Wet[i] = (k < NA) ? f2b(We[(size_t)k * HD + col]) : (unsigned short)0;
}

// ---------------- embedding (MFMA): Xb = bf16(h @ W_emb) ----------------
// block: 64 rows x 128 cols, 4 waves 2x2; K=32 (padded from 28)
__global__ __launch_bounds__(256) void k_embed(const float* __restrict__ h,
                                               const unsigned short* __restrict__ Wet,
                                               unsigned short* __restrict__ Xb) {
  int t = threadIdx.x;
  int lane = t & 63, w = t >> 6;
  int wr = w >> 1, wc = w & 1;
  int row0 = blockIdx.x * 64 + wr * 32;
  int col0 = wc * 64;
  int fr = lane & 15;
  int fk = (lane >> 4) * 8;

  f32x4 acc[2][4] = {};
  bf16x8 a[2];
#pragma unroll
  for (int rt = 0; rt < 2; rt++) {
    int row = row0 + rt * 16 + fr;
    const float* hp = h + (size_t)row * NA + fk;
    float4 p = *(const float4*)hp;                    // k = fk..fk+3 (always < 28)
    float4 q = make_float4(0.f, 0.f, 0.f, 0.f);
    if (fk < 24) q = *(const float4*)(hp + 4);        // k = fk+4..fk+7; fk==24 -> pad 0
    a[rt][0] = (short)f2b(p.x); a[rt][1] = (short)f2b(p.y);
    a[rt][2] = (short)f2b(p.z); a[rt][3] = (short)f2b(p.w);
    a[rt][4] = (short)f2b(q.x); a[rt][5] = (short)f2b(q.y);
    a[rt][6] = (short)f2b(q.z); a[rt][7] = (short)f2b(q.w);
  }
#pragma unroll
  for (int ct = 0; ct < 4; ct++) {
    int col = col0 + ct * 16 + fr;
    bf16x8 b = *(const bf16x8*)(Wet + (size_t)col * 32 + fk);
#pragma unroll
    for (int rt = 0; rt < 2; rt++)
      acc[rt][ct] = __builtin_amdgcn_mfma_f32_16x16x32_bf16(a[rt], b, acc[rt][ct], 0, 0, 0);
  }
  int oc = lane & 15, orb = (lane >> 4) * 4;
#pragma unroll
  for (int rt = 0; rt < 2; rt++) {
#pragma unroll
    for (int ct = 0; ct < 4; ct++) {
      int col = col0 + ct * 16 + oc;
#pragma unroll
      for (int r = 0; r < 4; r++) {
        int row = row0 + rt * 16 + orb + r;
        Xb[(size_t)row * HD + col] = f2b(acc[rt][ct][r]);
      }
    }
  }
}

// ---------------- dual GEMM (MFMA, swapped operands): ----------------
// Qb = bf16(Hb @ W1 + bias), Pb8 = fp8(Hb @ W2); W = [W1; W2] (256 x 128).
// wave = 32 nodes (2 A-frag tiles, B reused x2) x 64 cols; block = 64 nodes x 128.
__global__ __launch_bounds__(256) void k_pq(const unsigned short* __restrict__ Hb,
                                            uint* __restrict__ Pb8,
                                            unsigned short* __restrict__ Qb,
                                            const unsigned short* __restrict__ Wt,
                                            const float* __restrict__ bias) {
  int t = threadIdx.x;
  int lane = t & 63, w = t >> 6;
  int ng = w >> 1, cg = w & 1;
  int fr = lane & 15, fkg = lane >> 4;
  int n0 = blockIdx.x * 64 + ng * 32;

  f32x4 accQ[2][4] = {}, accP[2][4] = {};
#pragma unroll
  for (int ks = 0; ks < 4; ks++) {
    bf16x8 aH[2];
#pragma unroll
    for (int nt = 0; nt < 2; nt++)
      aH[nt] = *(const bf16x8*)(Hb + (size_t)(n0 + nt * 16 + fr) * HD + ks * 32 + fkg * 8);
#pragma unroll
    for (int ct = 0; ct < 4; ct++) {
      const unsigned short* wrow =
          Wt + (size_t)(cg * 64 + ct * 16 + fr) * 256 + ks * 32 + fkg * 8;
      bf16x8 b1 = *(const bf16x8*)wrow;           // W1: k in [0,128)
      bf16x8 b2 = *(const bf16x8*)(wrow + 128);   // W2: k in [128,256)
#pragma unroll
      for (int nt = 0; nt < 2; nt++) {
        accQ[nt][ct] = __builtin_amdgcn_mfma_f32_16x16x32_bf16(b1, aH[nt], accQ[nt][ct], 0, 0, 0);
        accP[nt][ct] = __builtin_amdgcn_mfma_f32_16x16x32_bf16(b2, aH[nt], accP[nt][ct], 0, 0, 0);
      }
    }
  }
  // epilogue: lane -> node = n0+nt*16+fr, channels c0..c0+3
#pragma unroll
  for (int nt = 0; nt < 2; nt++) {
    int node = n0 + nt * 16 + fr;
#pragma unroll
    for (int ct = 0; ct < 4; ct++) {
      int c0 = cg * 64 + ct * 16 + fkg * 4;
      float4 bv = *(const float4*)(bias + c0);
      uint2 q;
      q.x = pack2(accQ[nt][ct][0] + bv.x, accQ[nt][ct][1] + bv.y);
      q.y = pack2(accQ[nt][ct][2] + bv.z, accQ[nt][ct][3] + bv.w);
      *(uint2*)(Qb + (size_t)node * HD + c0) = q;
      Pb8[(size_t)node * 32 + (c0 >> 2)] =
          pk_fp8x4(accP[nt][ct][0], accP[nt][ct][1], accP[nt][ct][2], accP[nt][ct][3]);
    }
  }
}

// ---------------- gather (fp8 P, 4 edges/load) + layer epilogue ----------------
// one wave per node; lane = (eg = lane>>4: edge slot, cl = lane&15: uint2 col).
// Each wave-load covers 4 edges (16 lanes x 8B = one 128B fp8 row per edge slot).
// Main loop: 16 edges = 4 loads in flight; then 8 (2 loads); then predicated 4.
// O[v] = relu(Q[v] + mean P) * snorm + Hres; last layer: fused readout.
__global__ __launch_bounds__(256) void k_gapply(const uint2* __restrict__ Pg,
                      const uint4* __restrict__ Qg, const uint4* __restrict__ Hres,
                      uint4* __restrict__ Og,
                      const int* __restrict__ row_start, const int* __restrict__ deg,
                      const int* __restrict__ esrc, const float* __restrict__ inv_deg,
                      const float* __restrict__ snorm,
                      const float* __restrict__ wcv, const int* __restrict__ gid,
                      const float* __restrict__ inv_gcnt, float* __restrict__ out,
                      int last) {
  int v = blockIdx.x * 4 + (threadIdx.x >> 6);
  int lane = threadIdx.x & 63;
  int eg = lane >> 4;                       // edge slot 0..3
  int cl = lane & 15;                       // uint2 col: fp8 cols 8cl..8cl+7
  int rs = __builtin_amdgcn_readfirstlane(row_start[v]);
  int d  = __builtin_amdgcn_readfirstlane(deg[v]);
  float a0 = 0.f, a1 = 0.f, a2 = 0.f, a3 = 0.f;
  float a4 = 0.f, a5 = 0.f, a6 = 0.f, a7 = 0.f;

#define ACCX(X)                                                             \
  { f32x2 p0 = __builtin_amdgcn_cvt_pk_f32_fp8((int)(X).x, false);          \
    f32x2 p1 = __builtin_amdgcn_cvt_pk_f32_fp8((int)(X).x, true);           \
    f32x2 p2 = __builtin_amdgcn_cvt_pk_f32_fp8((int)(X).y, false);          \
    f32x2 p3 = __builtin_amdgcn_cvt_pk_f32_fp8((int)(X).y, true);           \
    a0 += p0[0]; a1 += p0[1]; a2 += p1[0]; a3 += p1[1];                     \
    a4 += p2[0]; a5 += p2[1]; a6 += p3[0]; a7 += p3[1]; }

  int e = 0;
  for (; e + 16 <= d; e += 16) {
    uint2 x[4];
#pragma unroll
    for (int j = 0; j < 4; j++) {
      int idx = esrc[rs + e + 4 * j + eg];
      x[j] = Pg[(size_t)idx * 16 + cl];
    }
#pragma unroll
    for (int j = 0; j < 4; j++) ACCX(x[j])
  }
  for (; e + 8 <= d; e += 8) {
    uint2 x[2];
#pragma unroll
    for (int j = 0; j < 2; j++) {
      int idx = esrc[rs + e + 4 * j + eg];
      x[j] = Pg[(size_t)idx * 16 + cl];
    }
#pragma unroll
    for (int j = 0; j < 2; j++) ACCX(x[j])
  }
  for (; e < d; e += 4) {
    uint2 x = make_uint2(0u, 0u);
    if (e + eg < d) {
      int idx = esrc[rs + e + eg];
      x = Pg[(size_t)idx * 16 + cl];
    }
    ACCX(x)
  }
#undef ACCX

  // reduce across the 4 edge slots
  a0 += __shfl_xor(a0, 16, 64);  a0 += __shfl_xor(a0, 32, 64);
  a1 += __shfl_xor(a1, 16, 64);  a1 += __shfl_xor(a1, 32, 64);
  a2 += __shfl_xor(a2, 16, 64);  a2 += __shfl_xor(a2, 32, 64);
  a3 += __shfl_xor(a3, 16, 64);  a3 += __shfl_xor(a3, 32, 64);
  a4 += __shfl_xor(a4, 16, 64);  a4 += __shfl_xor(a4, 32, 64);
  a5 += __shfl_xor(a5, 16, 64);  a5 += __shfl_xor(a5, 32, 64);
  a6 += __shfl_xor(a6, 16, 64);  a6 += __shfl_xor(a6, 32, 64);
  a7 += __shfl_xor(a7, 16, 64);  a7 += __shfl_xor(a7, 32, 64);

  if (eg == 0) {                            // lanes 0..15: full-row uint4 IO
    float id = inv_deg[v];
    float sn = snorm[v];
    uint4 q  = Qg[(size_t)v * 16 + cl];
    uint4 hr = Hres[(size_t)v * 16 + cl];
    float o0 = fmaxf(blo(q.x) + a0 * id, 0.f) * sn + blo(hr.x);
    float o1 = fmaxf(bhi(q.x) + a1 * id, 0.f) * sn + bhi(hr.x);
    float o2 = fmaxf(blo(q.y) + a2 * id, 0.f) * sn + blo(hr.y);
    float o3 = fmaxf(bhi(q.y) + a3 * id, 0.f) * sn + bhi(hr.y);
    float o4 = fmaxf(blo(q.z) + a4 * id, 0.f) * sn + blo(hr.z);
    float o5 = fmaxf(bhi(q.z) + a5 * id, 0.f) * sn + bhi(hr.z);
    float o6 = fmaxf(blo(q.w) + a6 * id, 0.f) * sn + blo(hr.w);
    float o7 = fmaxf(bhi(q.w) + a7 * id, 0.f) * sn + bhi(hr.w);
    if (!last) {
      uint4 o;
      o.x = pack2(o0, o1);
      o.y = pack2(o2, o3);
      o.z = pack2(o4, o5);
      o.w = pack2(o6, o7);
      Og[(size_t)v * 16 + cl] = o;
    } else {
      float4 w0 = *(const float4*)(wcv + 8 * cl);
      float4 w1 = *(const float4*)(wcv + 8 * cl + 4);
      float p = o0 * w0.x + o1 * w0.y + o2 * w0.z + o3 * w0.w
              + o4 * w1.x + o5 * w1.y + o6 * w1.z + o7 * w1.w;
      p += __shfl_xor(p, 8, 64);
      p += __shfl_xor(p, 4, 64);
      p += __shfl_xor(p, 2, 64);
      p += __shfl_xor(p, 1, 64);
      if (cl == 0) {
        int g = gid[v];
        atomicAdd(&out[g], p * inv_gcnt[g]);
      }
    }
  }
}

// ---------------- readout weight combo ----------------
__global__ void k_wcombo(const float* __restrict__ W_ro, const float* __restrict__ W_pred,
                         float* __restrict__ wcv) {
  int i = threadIdx.x;  // 128
  float a = 0.f;
  for (int j = 0; j < HD; j++) a += W_ro[i * HD + j] * W_pred[j];
  wcv[i] = a;
}

// ---------------- launch ----------------
extern "C" void kernel_launch(void* const* d_in, const int* in_sizes, int n_in,
                              void* d_out, int out_size, void* d_ws, size_t ws_size,
                              hipStream_t stream) {
  const float* h      = (const float*)d_in[0];
  const float* snorm  = (const float*)d_in[1];
  const float* W_emb  = (const float*)d_in[2];
  const float* W_node = (const float*)d_in[3];
  const float* b_node = (const float*)d_in[4];
  const float* W_ro   = (const float*)d_in[5];
  const float* W_pred = (const float*)d_in[6];
  const float* b_pred = (const float*)d_in[7];
  const int*   src    = (const int*)d_in[8];
  const int*   dst    = (const int*)d_in[9];
  const int*   gid    = (const int*)d_in[10];
  float* out = (float*)d_out;

  char* ws = (char*)d_ws;
  unsigned short* Xb   = (unsigned short*)(ws + OFF_XB);
  unsigned short* Yb   = (unsigned short*)(ws + OFF_YB);
  uint*  Pb8      = (uint*)(ws + OFF_PB);
  int*   esrc     = (int*)(ws + OFF_ESRC);
  int*   deg      = (int*)(ws + OFF_DEG);
  int*   gcnt     = (int*)(ws + OFF_GCNT);
  int*   row_s    = (int*)(ws + OFF_ROW);
  float* inv_deg  = (float*)(ws + OFF_IDEG);
  float* inv_gcnt = (float*)(ws + OFF_IGC);
  int*   bsum     = (int*)(ws + OFF_BSUM);
  int*   coff     = (int*)(ws + OFF_COFF);
  float* wcv      = (float*)(ws + OFF_WC);
  unsigned short* Wnt = (unsigned short*)(ws + OFF_WNT);
  uint*  ebuf     = (uint*)(ws + OFF_EBUF);
  int*   gcur     = (int*)(ws + OFF_GCUR);
  unsigned short* Wet = (unsigned short*)(ws + OFF_WET);

  hipMemsetAsync(ws + OFF_GCNT, 0, (size_t)NG * 4, stream);

  k_binit<<<1, NB, 0, stream>>>(gcur);
  k_bin<<<NE / 4096, 256, 0, stream>>>(src, dst, gcur, ebuf);
  k_deg<<<NB, 256, 0, stream>>>(gcur, ebuf, deg);
  k_scan1<<<NN / 1024, 256, 0, stream>>>(deg, bsum);
  k_scan2<<<1, 128, 0, stream>>>(bsum, coff);
  k_scan3<<<NN / 1024, 256, 0, stream>>>(deg, coff, row_s, inv_deg);
  k_place2<<<NB, 256, 0, stream>>>(gcur, ebuf, row_s, esrc);
  k_ghist<<<NN / 256, 256, 0, stream>>>(gid, gcnt);
  k_ginit<<<NG / 256, 256, 0, stream>>>(gcnt, inv_gcnt, out, b_pred);
  k_wprep<<<(NL * 256 * HD) / 256, 256, 0, stream>>>(W_node, Wnt);
  k_weprep<<<(HD * 32) / 256, 256, 0, stream>>>(W_emb, Wet);
  k_wcombo<<<1, 128, 0, stream>>>(W_ro, W_pred, wcv);

  k_embed<<<NN / 64, 256, 0, stream>>>(h, Wet, Xb);

  for (int l = 0; l < NL; l++) {
    unsigned short* hb = (l & 1) ? Yb : Xb;   // layer input
    unsigned short* qo = (l & 1) ? Xb : Yb;   // Q buffer, overwritten in-place by O
    k_pq<<<NN / 64, 256, 0, stream>>>(hb, Pb8, qo, Wnt + (size_t)l * HD * 256,
                                      b_node + (size_t)l * HD);
    k_gapply<<<NN / 4, 256, 0, stream>>>((const uint2*)Pb8, (const uint4*)qo,
                                         (const uint4*)hb, (uint4*)qo,
                                         row_s, deg, esrc, inv_deg, snorm,
                                         wcv, gid, inv_gcnt, out, (l == NL - 1) ? 1 : 0);
  }
}

// Round 12
// 562.005 us; speedup vs baseline: 1.3600x; 1.0451x over previous
//
#include <hip/hip_runtime.h>

// Problem constants
constexpr int NN  = 131072;   // nodes
constexpr int NE  = 2097152;  // edges
constexpr int HD  = 128;      // hidden
constexpr int NG  = 8192;     // graphs
constexpr int NA  = 28;       // atom types
constexpr int NL  = 4;        // layers

// CSR bucketing
constexpr int NB   = 256;     // buckets
constexpr int BSH  = 9;       // dst>>9 -> bucket (512 nodes/bucket)
constexpr int BNOD = 512;     // nodes per bucket
constexpr int CAP  = 10240;   // slots per bucket (mean 8192 + 22 sigma)

// ---------------- workspace layout (bytes) ----------------
constexpr size_t SZ_FB   = (size_t)NN * HD * 2;          // 32 MiB bf16 feature buf
constexpr size_t OFF_XB   = 0;
constexpr size_t OFF_YB   = OFF_XB + SZ_FB;
constexpr size_t OFF_PB   = OFF_YB + SZ_FB;              // P = H @ W2, fp8 e4m3 (16 MiB)
constexpr size_t OFF_ESRC = OFF_PB + SZ_FB;
constexpr size_t OFF_DEG  = OFF_ESRC + (size_t)NE * 4;
constexpr size_t OFF_GCNT = OFF_DEG + (size_t)NN * 4;
constexpr size_t OFF_ROW  = OFF_GCNT + (size_t)NG * 4;
constexpr size_t OFF_IDEG = OFF_ROW + (size_t)NN * 4;
constexpr size_t OFF_IGC  = OFF_IDEG + (size_t)NN * 4;
constexpr size_t OFF_BSUM = OFF_IGC + (size_t)NG * 4;
constexpr size_t OFF_COFF = OFF_BSUM + 512;
constexpr size_t OFF_WC   = OFF_COFF + 512;
constexpr size_t OFF_WNT  = OFF_WC + 512;                // bf16 W transposed [L][128][256]
constexpr size_t OFF_EBUF = OFF_WNT + (size_t)NL * HD * 256 * 2;
constexpr size_t OFF_GCUR = OFF_EBUF + (size_t)NB * CAP * 4;
constexpr size_t OFF_WET  = OFF_GCUR + (size_t)NB * 4;   // bf16 W_emb^T [128][32]

// ---------------- bf16 / fp8 helpers ----------------
__device__ __forceinline__ float blo(uint x) { return __uint_as_float(x << 16); }
__device__ __forceinline__ float bhi(uint x) { return __uint_as_float(x & 0xFFFF0000u); }
__device__ __forceinline__ unsigned short f2b(float f) {
  uint u = __float_as_uint(f);
  return (unsigned short)((u + 0x7FFFu + ((u >> 16) & 1u)) >> 16);
}
__device__ __forceinline__ uint pack2(float a, float b) {
  uint ua = __float_as_uint(a), ub = __float_as_uint(b);
  uint lo = (ua + 0x7FFFu + ((ua >> 16) & 1u)) >> 16;
  uint hi = (ub + 0x7FFFu + ((ub >> 16) & 1u)) & 0xFFFF0000u;
  return lo | hi;
}

typedef __attribute__((ext_vector_type(8))) short bf16x8;
typedef __attribute__((ext_vector_type(4))) float f32x4;
typedef __attribute__((ext_vector_type(2))) float f32x2;

// pack 4 f32 -> 4 fp8 e4m3 in one uint (2 HW instrs)
__device__ __forceinline__ uint pk_fp8x4(float a, float b, float c, float d) {
  int p = __builtin_amdgcn_cvt_pk_fp8_f32(a, b, 0, false);
  p = __builtin_amdgcn_cvt_pk_fp8_f32(c, d, p, true);
  return (uint)p;
}

// ---------------- CSR build: bucketed ----------------
__global__ void k_binit(int* __restrict__ gcur) {
  int b = threadIdx.x;           // 256
  gcur[b] = b * CAP;
}

// partition edges into NB buckets by dst>>BSH; packed = (dst&511)<<17 | src
__global__ __launch_bounds__(256) void k_bin(const int* __restrict__ src,
                                             const int* __restrict__ dst,
                                             int* __restrict__ gcur,
                                             uint* __restrict__ ebuf) {
  __shared__ int cnt[NB];
  __shared__ int gbase[NB];
  int t = threadIdx.x;
  cnt[t] = 0;
  int es[16], ed[16];
  int base = blockIdx.x * 4096 + t;
#pragma unroll
  for (int j = 0; j < 16; j++) {
    es[j] = src[base + j * 256];
    ed[j] = dst[base + j * 256];
  }
  __syncthreads();
#pragma unroll
  for (int j = 0; j < 16; j++) atomicAdd(&cnt[ed[j] >> BSH], 1);
  __syncthreads();
  int c = cnt[t];
  if (c > 0) gbase[t] = atomicAdd(&gcur[t], c);
  cnt[t] = 0;
  __syncthreads();
#pragma unroll
  for (int j = 0; j < 16; j++) {
    int b = ed[j] >> BSH;
    int r = atomicAdd(&cnt[b], 1);
    ebuf[(size_t)gbase[b] + r] = ((uint)(ed[j] & (BNOD - 1)) << 17) | (uint)es[j];
  }
}

// per-bucket degree histogram (LDS), coalesced deg writes, no global atomics
__global__ __launch_bounds__(256) void k_deg(const int* __restrict__ gcur,
                                             const uint* __restrict__ ebuf,
                                             int* __restrict__ deg) {
  __shared__ int h[BNOD];
  int b = blockIdx.x, t = threadIdx.x;
  h[t] = 0; h[t + 256] = 0;
  int n = gcur[b] - b * CAP;
  __syncthreads();
  const uint* eb = ebuf + (size_t)b * CAP;
  for (int i = t; i < n; i += 256) atomicAdd(&h[eb[i] >> 17], 1);
  __syncthreads();
  deg[b * BNOD + t] = h[t];
  deg[b * BNOD + t + 256] = h[t + 256];
}

__global__ void k_scan1(const int* __restrict__ deg, int* __restrict__ bsum) {
  __shared__ int s[256];
  int b = blockIdx.x, t = threadIdx.x;
  const int4* p = (const int4*)(deg + (size_t)b * 1024);
  int4 v = p[t];
  s[t] = v.x + v.y + v.z + v.w;
  __syncthreads();
  for (int o = 128; o > 0; o >>= 1) {
    if (t < o) s[t] += s[t + o];
    __syncthreads();
  }
  if (t == 0) bsum[b] = s[0];
}

__global__ void k_scan2(const int* __restrict__ bsum, int* __restrict__ coff) {
  __shared__ int s[128];
  int t = threadIdx.x;
  int mine = bsum[t];
  s[t] = mine;
  __syncthreads();
  for (int o = 1; o < 128; o <<= 1) {
    int v = (t >= o) ? s[t - o] : 0;
    __syncthreads();
    s[t] += v;
    __syncthreads();
  }
  coff[t] = s[t] - mine;  // exclusive
}

__global__ void k_scan3(const int* __restrict__ deg, const int* __restrict__ coff,
                        int* __restrict__ row_start, float* __restrict__ inv_deg) {
  __shared__ int s[256];
  int b = blockIdx.x, t = threadIdx.x;
  int base = b * 1024 + t * 4;
  const int4* p = (const int4*)(deg + base);
  int4 d = *p;
  int lsum = d.x + d.y + d.z + d.w;
  s[t] = lsum;
  __syncthreads();
  for (int o = 1; o < 256; o <<= 1) {
    int v = (t >= o) ? s[t - o] : 0;
    __syncthreads();
    s[t] += v;
    __syncthreads();
  }
  int pre = coff[b] + s[t] - lsum;
  int r0 = pre, r1 = r0 + d.x, r2 = r1 + d.y, r3 = r2 + d.z;
  row_start[base] = r0;  row_start[base + 1] = r1;
  row_start[base + 2] = r2;  row_start[base + 3] = r3;
  inv_deg[base]     = 1.0f / fmaxf((float)d.x, 1.0f);
  inv_deg[base + 1] = 1.0f / fmaxf((float)d.y, 1.0f);
  inv_deg[base + 2] = 1.0f / fmaxf((float)d.z, 1.0f);
  inv_deg[base + 3] = 1.0f / fmaxf((float)d.w, 1.0f);
}

// per-bucket placement: LDS cursors, esrc writes land in a 32KB window
__global__ __launch_bounds__(256) void k_place2(const int* __restrict__ gcur,
                                                const uint* __restrict__ ebuf,
                                                const int* __restrict__ row_start,
                                                int* __restrict__ esrc) {
  __shared__ int cur[BNOD];
  int b = blockIdx.x, t = threadIdx.x;
  cur[t] = row_start[b * BNOD + t];
  cur[t + 256] = row_start[b * BNOD + t + 256];
  int n = gcur[b] - b * CAP;
  __syncthreads();
  const uint* eb = ebuf + (size_t)b * CAP;
  for (int i = t; i < n; i += 256) {
    uint p = eb[i];
    int r = atomicAdd(&cur[p >> 17], 1);
    esrc[r] = (int)(p & 0x1FFFFu);
  }
}

__global__ void k_ghist(const int* __restrict__ gid, int* __restrict__ gcnt) {
  int i = blockIdx.x * blockDim.x + threadIdx.x;
  if (i < NN) atomicAdd(&gcnt[gid[i]], 1);
}

__global__ void k_ginit(const int* __restrict__ gcnt, float* __restrict__ inv_gcnt,
                        float* __restrict__ out, const float* __restrict__ b_pred) {
  int g = blockIdx.x * blockDim.x + threadIdx.x;
  if (g < NG) {
    inv_gcnt[g] = 1.0f / fmaxf((float)gcnt[g], 1.0f);
    out[g] = b_pred[0];
  }
}

// ---------------- weight prep ----------------
// Wnt[l][c][k] = bf16(W_node[l][k][c])
__global__ void k_wprep(const float* __restrict__ Wn, unsigned short* __restrict__ Wnt) {
  int i = blockIdx.x * 256 + threadIdx.x;   // L*256*128 total
  int l = i >> 15;
  int k = (i >> 7) & 255;
  int c = i & 127;
  float v = Wn[((size_t)l * 256 + k) * HD + c];
  Wnt[((size_t)l * HD + c) * 256 + k] = f2b(v);
}

// Wet[c][k] = bf16(W_emb[k][c]), k padded 28->32 with zeros
__global__ void k_weprep(const float* __restrict__ We, unsigned short* __restrict__ Wet) {
  int i = blockIdx.x * 256 + threadIdx.x;   // 128*32 = 4096 total
  int col = i >> 5, k = i & 31;
  Wet[i] = (k < NA) ? f2b(We[(size_t)k * HD + col]) : (unsigned short)0;
}

// ---------------- embedding (MFMA): Xb = bf16(h @ W_emb) ----------------
// block: 64 rows x 128 cols, 4 waves 2x2; K=32 (padded from 28)
__global__ __launch_bounds__(256) void k_embed(const float* __restrict__ h,
                                               const unsigned short* __restrict__ Wet,
                                               unsigned short* __restrict__ Xb) {
  int t = threadIdx.x;
  int lane = t & 63, w = t >> 6;
  int wr = w >> 1, wc = w & 1;
  int row0 = blockIdx.x * 64 + wr * 32;
  int col0 = wc * 64;
  int fr = lane & 15;
  int fk = (lane >> 4) * 8;

  f32x4 acc[2][4] = {};
  bf16x8 a[2];
#pragma unroll
  for (int rt = 0; rt < 2; rt++) {
    int row = row0 + rt * 16 + fr;
    const float* hp = h + (size_t)row * NA + fk;
    float4 p = *(const float4*)hp;                    // k = fk..fk+3 (always < 28)
    float4 q = make_float4(0.f, 0.f, 0.f, 0.f);
    if (fk < 24) q = *(const float4*)(hp + 4);        // k = fk+4..fk+7; fk==24 -> pad 0
    a[rt][0] = (short)f2b(p.x); a[rt][1] = (short)f2b(p.y);
    a[rt][2] = (short)f2b(p.z); a[rt][3] = (short)f2b(p.w);
    a[rt][4] = (short)f2b(q.x); a[rt][5] = (short)f2b(q.y);
    a[rt][6] = (short)f2b(q.z); a[rt][7] = (short)f2b(q.w);
  }
#pragma unroll
  for (int ct = 0; ct < 4; ct++) {
    int col = col0 + ct * 16 + fr;
    bf16x8 b = *(const bf16x8*)(Wet + (size_t)col * 32 + fk);
#pragma unroll
    for (int rt = 0; rt < 2; rt++)
      acc[rt][ct] = __builtin_amdgcn_mfma_f32_16x16x32_bf16(a[rt], b, acc[rt][ct], 0, 0, 0);
  }
  int oc = lane & 15, orb = (lane >> 4) * 4;
#pragma unroll
  for (int rt = 0; rt < 2; rt++) {
#pragma unroll
    for (int ct = 0; ct < 4; ct++) {
      int col = col0 + ct * 16 + oc;
#pragma unroll
      for (int r = 0; r < 4; r++) {
        int row = row0 + rt * 16 + orb + r;
        Xb[(size_t)row * HD + col] = f2b(acc[rt][ct][r]);
      }
    }
  }
}

// ---------------- dual GEMM (MFMA, swapped operands): ----------------
// Qb = bf16(Hb @ W1 + bias), Pb8 = fp8(Hb @ W2); W = [W1; W2] (256 x 128).
// wave = 32 nodes (2 A-frag tiles, B reused x2) x 64 cols; block = 64 nodes x 128.
__global__ __launch_bounds__(256) void k_pq(const unsigned short* __restrict__ Hb,
                                            uint* __restrict__ Pb8,
                                            unsigned short* __restrict__ Qb,
                                            const unsigned short* __restrict__ Wt,
                                            const float* __restrict__ bias) {
  int t = threadIdx.x;
  int lane = t & 63, w = t >> 6;
  int ng = w >> 1, cg = w & 1;
  int fr = lane & 15, fkg = lane >> 4;
  int n0 = blockIdx.x * 64 + ng * 32;

  f32x4 accQ[2][4] = {}, accP[2][4] = {};
#pragma unroll
  for (int ks = 0; ks < 4; ks++) {
    bf16x8 aH[2];
#pragma unroll
    for (int nt = 0; nt < 2; nt++)
      aH[nt] = *(const bf16x8*)(Hb + (size_t)(n0 + nt * 16 + fr) * HD + ks * 32 + fkg * 8);
#pragma unroll
    for (int ct = 0; ct < 4; ct++) {
      const unsigned short* wrow =
          Wt + (size_t)(cg * 64 + ct * 16 + fr) * 256 + ks * 32 + fkg * 8;
      bf16x8 b1 = *(const bf16x8*)wrow;           // W1: k in [0,128)
      bf16x8 b2 = *(const bf16x8*)(wrow + 128);   // W2: k in [128,256)
#pragma unroll
      for (int nt = 0; nt < 2; nt++) {
        accQ[nt][ct] = __builtin_amdgcn_mfma_f32_16x16x32_bf16(b1, aH[nt], accQ[nt][ct], 0, 0, 0);
        accP[nt][ct] = __builtin_amdgcn_mfma_f32_16x16x32_bf16(b2, aH[nt], accP[nt][ct], 0, 0, 0);
      }
    }
  }
  // epilogue: lane -> node = n0+nt*16+fr, channels c0..c0+3
#pragma unroll
  for (int nt = 0; nt < 2; nt++) {
    int node = n0 + nt * 16 + fr;
#pragma unroll
    for (int ct = 0; ct < 4; ct++) {
      int c0 = cg * 64 + ct * 16 + fkg * 4;
      float4 bv = *(const float4*)(bias + c0);
      uint2 q;
      q.x = pack2(accQ[nt][ct][0] + bv.x, accQ[nt][ct][1] + bv.y);
      q.y = pack2(accQ[nt][ct][2] + bv.z, accQ[nt][ct][3] + bv.w);
      *(uint2*)(Qb + (size_t)node * HD + c0) = q;
      Pb8[(size_t)node * 32 + (c0 >> 2)] =
          pk_fp8x4(accP[nt][ct][0], accP[nt][ct][1], accP[nt][ct][2], accP[nt][ct][3]);
    }
  }
}

// ---------------- gather (fp8 P) + layer epilogue, v3 ----------------
// one wave per node; lane = (eg = lane>>4: edge slot, cl = lane&15: uint2 col).
// v3: (1) Q/Hres/snorm/inv_deg loads hoisted BEFORE the gather (latency hidden
// under it); (2) edge indices preloaded once via a single coalesced load
// (d<=64 in practice) + shfl broadcast -> no dependent esrc load per batch.
__global__ __launch_bounds__(256) void k_gapply(const uint2* __restrict__ Pg,
                      const uint4* __restrict__ Qg, const uint4* __restrict__ Hres,
                      uint4* __restrict__ Og,
                      const int* __restrict__ row_start, const int* __restrict__ deg,
                      const int* __restrict__ esrc, const float* __restrict__ inv_deg,
                      const float* __restrict__ snorm,
                      const float* __restrict__ wcv, const int* __restrict__ gid,
                      const float* __restrict__ inv_gcnt, float* __restrict__ out,
                      int last) {
  int v = blockIdx.x * 4 + (threadIdx.x >> 6);
  int lane = threadIdx.x & 63;
  int eg = lane >> 4;                       // edge slot 0..3
  int cl = lane & 15;                       // uint2 col: fp8 cols 8cl..8cl+7
  int rs = __builtin_amdgcn_readfirstlane(row_start[v]);
  int d  = __builtin_amdgcn_readfirstlane(deg[v]);

  // ---- hoisted epilogue operands (latency hides under the gather) ----
  float id = inv_deg[v];
  float sn = snorm[v];
  uint4 q  = Qg[(size_t)v * 16 + cl];       // lanes 16+ replicate -> coalesced
  uint4 hr = Hres[(size_t)v * 16 + cl];

  // ---- coalesced index preload: all of this node's edges in one load ----
  int dcap = min(d, 64);
  int myidx = 0;
  if (lane < dcap) myidx = esrc[rs + lane];

  float a0 = 0.f, a1 = 0.f, a2 = 0.f, a3 = 0.f;
  float a4 = 0.f, a5 = 0.f, a6 = 0.f, a7 = 0.f;

#define ACCX(X)                                                             \
  { f32x2 p0 = __builtin_amdgcn_cvt_pk_f32_fp8((int)(X).x, false);          \
    f32x2 p1 = __builtin_amdgcn_cvt_pk_f32_fp8((int)(X).x, true);           \
    f32x2 p2 = __builtin_amdgcn_cvt_pk_f32_fp8((int)(X).y, false);          \
    f32x2 p3 = __builtin_amdgcn_cvt_pk_f32_fp8((int)(X).y, true);           \
    a0 += p0[0]; a1 += p0[1]; a2 += p1[0]; a3 += p1[1];                     \
    a4 += p2[0]; a5 += p2[1]; a6 += p3[0]; a7 += p3[1]; }

  int e = 0;
  for (; e + 8 <= dcap; e += 8) {           // 8 edges = 2 loads in flight
    int i0 = __shfl(myidx, e + eg, 64);
    int i1 = __shfl(myidx, e + 4 + eg, 64);
    uint2 x0 = Pg[(size_t)i0 * 16 + cl];
    uint2 x1 = Pg[(size_t)i1 * 16 + cl];
    ACCX(x0)
    ACCX(x1)
  }
  if (e + 4 <= dcap) {
    int i0 = __shfl(myidx, e + eg, 64);
    uint2 x = Pg[(size_t)i0 * 16 + cl];
    ACCX(x)
    e += 4;
  }
  if (e < dcap) {                           // masked tail (<4 edges)
    uint2 x = make_uint2(0u, 0u);
    if (e + eg < dcap) {
      int i0 = __shfl(myidx, e + eg, 64);
      x = Pg[(size_t)i0 * 16 + cl];
    }
    ACCX(x)
  }
  for (int ee = 64; ee < d; ee += 4) {      // d>64: essentially never (Poisson 16)
    uint2 x = make_uint2(0u, 0u);
    if (ee + eg < d) x = Pg[(size_t)esrc[rs + ee + eg] * 16 + cl];
    ACCX(x)
  }
#undef ACCX

  // reduce across the 4 edge slots
  a0 += __shfl_xor(a0, 16, 64);  a0 += __shfl_xor(a0, 32, 64);
  a1 += __shfl_xor(a1, 16, 64);  a1 += __shfl_xor(a1, 32, 64);
  a2 += __shfl_xor(a2, 16, 64);  a2 += __shfl_xor(a2, 32, 64);
  a3 += __shfl_xor(a3, 16, 64);  a3 += __shfl_xor(a3, 32, 64);
  a4 += __shfl_xor(a4, 16, 64);  a4 += __shfl_xor(a4, 32, 64);
  a5 += __shfl_xor(a5, 16, 64);  a5 += __shfl_xor(a5, 32, 64);
  a6 += __shfl_xor(a6, 16, 64);  a6 += __shfl_xor(a6, 32, 64);
  a7 += __shfl_xor(a7, 16, 64);  a7 += __shfl_xor(a7, 32, 64);

  if (eg == 0) {                            // lanes 0..15: full-row uint4 IO
    float o0 = fmaxf(blo(q.x) + a0 * id, 0.f) * sn + blo(hr.x);
    float o1 = fmaxf(bhi(q.x) + a1 * id, 0.f) * sn + bhi(hr.x);
    float o2 = fmaxf(blo(q.y) + a2 * id, 0.f) * sn + blo(hr.y);
    float o3 = fmaxf(bhi(q.y) + a3 * id, 0.f) * sn + bhi(hr.y);
    float o4 = fmaxf(blo(q.z) + a4 * id, 0.f) * sn + blo(hr.z);
    float o5 = fmaxf(bhi(q.z) + a5 * id, 0.f) * sn + bhi(hr.z);
    float o6 = fmaxf(blo(q.w) + a6 * id, 0.f) * sn + blo(hr.w);
    float o7 = fmaxf(bhi(q.w) + a7 * id, 0.f) * sn + bhi(hr.w);
    if (!last) {
      uint4 o;
      o.x = pack2(o0, o1);
      o.y = pack2(o2, o3);
      o.z = pack2(o4, o5);
      o.w = pack2(o6, o7);
      Og[(size_t)v * 16 + cl] = o;
    } else {
      float4 w0 = *(const float4*)(wcv + 8 * cl);
      float4 w1 = *(const float4*)(wcv + 8 * cl + 4);
      float p = o0 * w0.x + o1 * w0.y + o2 * w0.z + o3 * w0.w
              + o4 * w1.x + o5 * w1.y + o6 * w1.z + o7 * w1.w;
      p += __shfl_xor(p, 8, 64);
      p += __shfl_xor(p, 4, 64);
      p += __shfl_xor(p, 2, 64);
      p += __shfl_xor(p, 1, 64);
      if (cl == 0) {
        int g = gid[v];
        atomicAdd(&out[g], p * inv_gcnt[g]);
      }
    }
  }
}

// ---------------- readout weight combo ----------------
__global__ void k_wcombo(const float* __restrict__ W_ro, const float* __restrict__ W_pred,
                         float* __restrict__ wcv) {
  int i = threadIdx.x;  // 128
  float a = 0.f;
  for (int j = 0; j < HD; j++) a += W_ro[i * HD + j] * W_pred[j];
  wcv[i] = a;
}

// ---------------- launch ----------------
extern "C" void kernel_launch(void* const* d_in, const int* in_sizes, int n_in,
                              void* d_out, int out_size, void* d_ws, size_t ws_size,
                              hipStream_t stream) {
  const float* h      = (const float*)d_in[0];
  const float* snorm  = (const float*)d_in[1];
  const float* W_emb  = (const float*)d_in[2];
  const float* W_node = (const float*)d_in[3];
  const float* b_node = (const float*)d_in[4];
  const float* W_ro   = (const float*)d_in[5];
  const float* W_pred = (const float*)d_in[6];
  const float* b_pred = (const float*)d_in[7];
  const int*   src    = (const int*)d_in[8];
  const int*   dst    = (const int*)d_in[9];
  const int*   gid    = (const int*)d_in[10];
  float* out = (float*)d_out;

  char* ws = (char*)d_ws;
  unsigned short* Xb   = (unsigned short*)(ws + OFF_XB);
  unsigned short* Yb   = (unsigned short*)(ws + OFF_YB);
  uint*  Pb8      = (uint*)(ws + OFF_PB);
  int*   esrc     = (int*)(ws + OFF_ESRC);
  int*   deg      = (int*)(ws + OFF_DEG);
  int*   gcnt     = (int*)(ws + OFF_GCNT);
  int*   row_s    = (int*)(ws + OFF_ROW);
  float* inv_deg  = (float*)(ws + OFF_IDEG);
  float* inv_gcnt = (float*)(ws + OFF_IGC);
  int*   bsum     = (int*)(ws + OFF_BSUM);
  int*   coff     = (int*)(ws + OFF_COFF);
  float* wcv      = (float*)(ws + OFF_WC);
  unsigned short* Wnt = (unsigned short*)(ws + OFF_WNT);
  uint*  ebuf     = (uint*)(ws + OFF_EBUF);
  int*   gcur     = (int*)(ws + OFF_GCUR);
  unsigned short* Wet = (unsigned short*)(ws + OFF_WET);

  hipMemsetAsync(ws + OFF_GCNT, 0, (size_t)NG * 4, stream);

  k_binit<<<1, NB, 0, stream>>>(gcur);
  k_bin<<<NE / 4096, 256, 0, stream>>>(src, dst, gcur, ebuf);
  k_deg<<<NB, 256, 0, stream>>>(gcur, ebuf, deg);
  k_scan1<<<NN / 1024, 256, 0, stream>>>(deg, bsum);
  k_scan2<<<1, 128, 0, stream>>>(bsum, coff);
  k_scan3<<<NN / 1024, 256, 0, stream>>>(deg, coff, row_s, inv_deg);
  k_place2<<<NB, 256, 0, stream>>>(gcur, ebuf, row_s, esrc);
  k_ghist<<<NN / 256, 256, 0, stream>>>(gid, gcnt);
  k_ginit<<<NG / 256, 256, 0, stream>>>(gcnt, inv_gcnt, out, b_pred);
  k_wprep<<<(NL * 256 * HD) / 256, 256, 0, stream>>>(W_node, Wnt);
  k_weprep<<<(HD * 32) / 256, 256, 0, stream>>>(W_emb, Wet);
  k_wcombo<<<1, 128, 0, stream>>>(W_ro, W_pred, wcv);

  k_embed<<<NN / 64, 256, 0, stream>>>(h, Wet, Xb);

  for (int l = 0; l < NL; l++) {
    unsigned short* hb = (l & 1) ? Yb : Xb;   // layer input
    unsigned short* qo = (l & 1) ? Xb : Yb;   // Q buffer, overwritten in-place by O
    k_pq<<<NN / 64, 256, 0, stream>>>(hb, Pb8, qo, Wnt + (size_t)l * HD * 256,
                                      b_node + (size_t)l * HD);
    k_gapply<<<NN / 4, 256, 0, stream>>>((const uint2*)Pb8, (const uint4*)qo,
                                         (const uint4*)hb, (uint4*)qo,
                                         row_s, deg, esrc, inv_deg, snorm,
                                         wcv, gid, inv_gcnt, out, (l == NL - 1) ? 1 : 0);
  }
}

// Round 13
// 539.728 us; speedup vs baseline: 1.4161x; 1.0413x over previous
//
#include <hip/hip_runtime.h>

// Problem constants
constexpr int NN  = 131072;   // nodes
constexpr int NE  = 2097152;  // edges
constexpr int HD  = 128;      // hidden
constexpr int NG  = 8192;     // graphs
constexpr int NA  = 28;       // atom types
constexpr int NL  = 4;        // layers

// CSR bucketing
constexpr int NB   = 256;     // buckets
constexpr int BSH  = 9;       // dst>>9 -> bucket (512 nodes/bucket)
constexpr int BNOD = 512;     // nodes per bucket
constexpr int CAP  = 10240;   // slots per bucket (mean 8192 + 22 sigma)

// ---------------- workspace layout (bytes) ----------------
constexpr size_t SZ_FB   = (size_t)NN * HD * 2;          // 32 MiB bf16 feature buf
constexpr size_t OFF_XB   = 0;
constexpr size_t OFF_YB   = OFF_XB + SZ_FB;
constexpr size_t OFF_PB   = OFF_YB + SZ_FB;              // P = H @ W2, fp8 e4m3 (16 MiB)
constexpr size_t OFF_ESRC = OFF_PB + SZ_FB;
constexpr size_t OFF_DEG  = OFF_ESRC + (size_t)NE * 4;
constexpr size_t OFF_GCNT = OFF_DEG + (size_t)NN * 4;
constexpr size_t OFF_ROW  = OFF_GCNT + (size_t)NG * 4;
constexpr size_t OFF_IDEG = OFF_ROW + (size_t)NN * 4;
constexpr size_t OFF_IGC  = OFF_IDEG + (size_t)NN * 4;
constexpr size_t OFF_WC   = OFF_IGC + (size_t)NG * 4;
constexpr size_t OFF_WNT  = OFF_WC + 512;                // bf16 W transposed [L][128][256]
constexpr size_t OFF_EBUF = OFF_WNT + (size_t)NL * HD * 256 * 2;
constexpr size_t OFF_GCUR = OFF_EBUF + (size_t)NB * CAP * 4;
constexpr size_t OFF_WET  = OFF_GCUR + (size_t)NB * 4;   // bf16 W_emb^T [128][32]

// ---------------- bf16 / fp8 helpers ----------------
__device__ __forceinline__ float blo(uint x) { return __uint_as_float(x << 16); }
__device__ __forceinline__ float bhi(uint x) { return __uint_as_float(x & 0xFFFF0000u); }
__device__ __forceinline__ unsigned short f2b(float f) {
  uint u = __float_as_uint(f);
  return (unsigned short)((u + 0x7FFFu + ((u >> 16) & 1u)) >> 16);
}
__device__ __forceinline__ uint pack2(float a, float b) {
  uint ua = __float_as_uint(a), ub = __float_as_uint(b);
  uint lo = (ua + 0x7FFFu + ((ua >> 16) & 1u)) >> 16;
  uint hi = (ub + 0x7FFFu + ((ub >> 16) & 1u)) & 0xFFFF0000u;
  return lo | hi;
}

typedef __attribute__((ext_vector_type(8))) short bf16x8;
typedef __attribute__((ext_vector_type(4))) float f32x4;
typedef __attribute__((ext_vector_type(2))) float f32x2;

// pack 4 f32 -> 4 fp8 e4m3 in one uint (2 HW instrs)
__device__ __forceinline__ uint pk_fp8x4(float a, float b, float c, float d) {
  int p = __builtin_amdgcn_cvt_pk_fp8_f32(a, b, 0, false);
  p = __builtin_amdgcn_cvt_pk_fp8_f32(c, d, p, true);
  return (uint)p;
}

// ---------------- graph-id histogram (needs zeroed gcnt) ----------------
__global__ void k_ghist(const int* __restrict__ gid, int* __restrict__ gcnt) {
  int i = blockIdx.x * blockDim.x + threadIdx.x;
  if (i < NN) atomicAdd(&gcnt[gid[i]], 1);
}

// ---------------- fused setup: gcur init / ginit / wprep / weprep / wcombo ----
// grid = 1 + NG/256 + 512 + 16 + 1 = 562 blocks, branch by block range.
__global__ void k_prep(int* __restrict__ gcur, const int* __restrict__ gcnt,
                       float* __restrict__ inv_gcnt, float* __restrict__ out,
                       const float* __restrict__ b_pred,
                       const float* __restrict__ Wn, unsigned short* __restrict__ Wnt,
                       const float* __restrict__ We, unsigned short* __restrict__ Wet,
                       const float* __restrict__ W_ro, const float* __restrict__ W_pred,
                       float* __restrict__ wcv) {
  int bi = blockIdx.x, t = threadIdx.x;
  if (bi == 0) {
    gcur[t] = t * CAP;
  } else if (bi < 1 + NG / 256) {
    int g = (bi - 1) * 256 + t;
    inv_gcnt[g] = 1.0f / fmaxf((float)gcnt[g], 1.0f);
    out[g] = b_pred[0];
  } else if (bi < 1 + NG / 256 + 512) {
    int i = (bi - 1 - NG / 256) * 256 + t;        // L*256*128 total
    int l = i >> 15, k = (i >> 7) & 255, c = i & 127;
    Wnt[((size_t)l * HD + c) * 256 + k] = f2b(Wn[((size_t)l * 256 + k) * HD + c]);
  } else if (bi < 1 + NG / 256 + 512 + 16) {
    int i = (bi - 1 - NG / 256 - 512) * 256 + t;  // 128*32 total
    int col = i >> 5, k = i & 31;
    Wet[i] = (k < NA) ? f2b(We[(size_t)k * HD + col]) : (unsigned short)0;
  } else {
    if (t < 128) {
      float a = 0.f;
      for (int j = 0; j < HD; j++) a += W_ro[t * HD + j] * W_pred[j];
      wcv[t] = a;
    }
  }
}

// ---------------- bin edges into NB buckets by dst>>BSH ----------------
// packed = (dst&511)<<17 | src
__global__ __launch_bounds__(256) void k_bin(const int* __restrict__ src,
                                             const int* __restrict__ dst,
                                             int* __restrict__ gcur,
                                             uint* __restrict__ ebuf) {
  __shared__ int cnt[NB];
  __shared__ int gbase[NB];
  int t = threadIdx.x;
  cnt[t] = 0;
  int es[16], ed[16];
  int base = blockIdx.x * 4096 + t;
#pragma unroll
  for (int j = 0; j < 16; j++) {
    es[j] = src[base + j * 256];
    ed[j] = dst[base + j * 256];
  }
  __syncthreads();
#pragma unroll
  for (int j = 0; j < 16; j++) atomicAdd(&cnt[ed[j] >> BSH], 1);
  __syncthreads();
  int c = cnt[t];
  if (c > 0) gbase[t] = atomicAdd(&gcur[t], c);
  cnt[t] = 0;
  __syncthreads();
#pragma unroll
  for (int j = 0; j < 16; j++) {
    int b = ed[j] >> BSH;
    int r = atomicAdd(&cnt[b], 1);
    ebuf[(size_t)gbase[b] + r] = ((uint)(ed[j] & (BNOD - 1)) << 17) | (uint)es[j];
  }
}

// ---------------- fused CSR: hist + scans + row_start/deg/inv_deg + place ------
// one block per bucket; esrc laid out bucket-major (transparent via row_start).
__global__ __launch_bounds__(256) void k_csr(const int* __restrict__ gcur,
                                             const uint* __restrict__ ebuf,
                                             int* __restrict__ deg,
                                             int* __restrict__ row_start,
                                             float* __restrict__ inv_deg,
                                             int* __restrict__ esrc) {
  __shared__ int h[BNOD];      // histogram, later cursors
  __shared__ int ps[NB];       // pair-sum scan
  __shared__ int bs[NB];       // bucket-size scan
  int b = blockIdx.x, t = threadIdx.x;

  bs[t] = gcur[t] - t * CAP;   // bucket sizes
  h[t] = 0; h[t + 256] = 0;
  __syncthreads();
  for (int o = 1; o < 256; o <<= 1) {         // inclusive scan of bucket sizes
    int v = (t >= o) ? bs[t - o] : 0;
    __syncthreads();
    bs[t] += v;
    __syncthreads();
  }
  int boff = (b == 0) ? 0 : bs[b - 1];
  int n = gcur[b] - b * CAP;

  const uint* eb = ebuf + (size_t)b * CAP;
  for (int i = t; i < n; i += 256) atomicAdd(&h[eb[i] >> 17], 1);
  __syncthreads();

  int d0 = h[2 * t], d1 = h[2 * t + 1];
  ps[t] = d0 + d1;
  __syncthreads();
  for (int o = 1; o < 256; o <<= 1) {         // inclusive scan of node pairs
    int v = (t >= o) ? ps[t - o] : 0;
    __syncthreads();
    ps[t] += v;
    __syncthreads();
  }
  int excl = ps[t] - (d0 + d1);
  int r0 = boff + excl, r1 = r0 + d0;
  int v0 = b * BNOD + 2 * t;
  deg[v0] = d0;  deg[v0 + 1] = d1;
  row_start[v0] = r0;  row_start[v0 + 1] = r1;
  inv_deg[v0]     = 1.0f / fmaxf((float)d0, 1.0f);
  inv_deg[v0 + 1] = 1.0f / fmaxf((float)d1, 1.0f);
  __syncthreads();
  h[2 * t] = r0;  h[2 * t + 1] = r1;          // cursors
  __syncthreads();
  for (int i = t; i < n; i += 256) {
    uint p = eb[i];
    int r = atomicAdd(&h[p >> 17], 1);
    esrc[r] = (int)(p & 0x1FFFFu);
  }
}

// ---------------- embedding (MFMA): Xb = bf16(h @ W_emb) ----------------
// block: 64 rows x 128 cols, 4 waves 2x2; K=32 (padded from 28)
__global__ __launch_bounds__(256) void k_embed(const float* __restrict__ h,
                                               const unsigned short* __restrict__ Wet,
                                               unsigned short* __restrict__ Xb) {
  int t = threadIdx.x;
  int lane = t & 63, w = t >> 6;
  int wr = w >> 1, wc = w & 1;
  int row0 = blockIdx.x * 64 + wr * 32;
  int col0 = wc * 64;
  int fr = lane & 15;
  int fk = (lane >> 4) * 8;

  f32x4 acc[2][4] = {};
  bf16x8 a[2];
#pragma unroll
  for (int rt = 0; rt < 2; rt++) {
    int row = row0 + rt * 16 + fr;
    const float* hp = h + (size_t)row * NA + fk;
    float4 p = *(const float4*)hp;                    // k = fk..fk+3 (always < 28)
    float4 q = make_float4(0.f, 0.f, 0.f, 0.f);
    if (fk < 24) q = *(const float4*)(hp + 4);        // k = fk+4..fk+7; fk==24 -> pad 0
    a[rt][0] = (short)f2b(p.x); a[rt][1] = (short)f2b(p.y);
    a[rt][2] = (short)f2b(p.z); a[rt][3] = (short)f2b(p.w);
    a[rt][4] = (short)f2b(q.x); a[rt][5] = (short)f2b(q.y);
    a[rt][6] = (short)f2b(q.z); a[rt][7] = (short)f2b(q.w);
  }
#pragma unroll
  for (int ct = 0; ct < 4; ct++) {
    int col = col0 + ct * 16 + fr;
    bf16x8 b = *(const bf16x8*)(Wet + (size_t)col * 32 + fk);
#pragma unroll
    for (int rt = 0; rt < 2; rt++)
      acc[rt][ct] = __builtin_amdgcn_mfma_f32_16x16x32_bf16(a[rt], b, acc[rt][ct], 0, 0, 0);
  }
  int oc = lane & 15, orb = (lane >> 4) * 4;
#pragma unroll
  for (int rt = 0; rt < 2; rt++) {
#pragma unroll
    for (int ct = 0; ct < 4; ct++) {
      int col = col0 + ct * 16 + oc;
#pragma unroll
      for (int r = 0; r < 4; r++) {
        int row = row0 + rt * 16 + orb + r;
        Xb[(size_t)row * HD + col] = f2b(acc[rt][ct][r]);
      }
    }
  }
}

// ---------------- dual GEMM (MFMA, swapped operands): ----------------
// Qb = bf16(Hb @ W1 + bias), Pb8 = fp8(Hb @ W2); W = [W1; W2] (256 x 128).
// wave = 32 nodes (2 A-frag tiles, B reused x2) x 64 cols; block = 64 nodes x 128.
__global__ __launch_bounds__(256) void k_pq(const unsigned short* __restrict__ Hb,
                                            uint* __restrict__ Pb8,
                                            unsigned short* __restrict__ Qb,
                                            const unsigned short* __restrict__ Wt,
                                            const float* __restrict__ bias) {
  int t = threadIdx.x;
  int lane = t & 63, w = t >> 6;
  int ng = w >> 1, cg = w & 1;
  int fr = lane & 15, fkg = lane >> 4;
  int n0 = blockIdx.x * 64 + ng * 32;

  f32x4 accQ[2][4] = {}, accP[2][4] = {};
#pragma unroll
  for (int ks = 0; ks < 4; ks++) {
    bf16x8 aH[2];
#pragma unroll
    for (int nt = 0; nt < 2; nt++)
      aH[nt] = *(const bf16x8*)(Hb + (size_t)(n0 + nt * 16 + fr) * HD + ks * 32 + fkg * 8);
#pragma unroll
    for (int ct = 0; ct < 4; ct++) {
      const unsigned short* wrow =
          Wt + (size_t)(cg * 64 + ct * 16 + fr) * 256 + ks * 32 + fkg * 8;
      bf16x8 b1 = *(const bf16x8*)wrow;           // W1: k in [0,128)
      bf16x8 b2 = *(const bf16x8*)(wrow + 128);   // W2: k in [128,256)
#pragma unroll
      for (int nt = 0; nt < 2; nt++) {
        accQ[nt][ct] = __builtin_amdgcn_mfma_f32_16x16x32_bf16(b1, aH[nt], accQ[nt][ct], 0, 0, 0);
        accP[nt][ct] = __builtin_amdgcn_mfma_f32_16x16x32_bf16(b2, aH[nt], accP[nt][ct], 0, 0, 0);
      }
    }
  }
  // epilogue: lane -> node = n0+nt*16+fr, channels c0..c0+3
#pragma unroll
  for (int nt = 0; nt < 2; nt++) {
    int node = n0 + nt * 16 + fr;
#pragma unroll
    for (int ct = 0; ct < 4; ct++) {
      int c0 = cg * 64 + ct * 16 + fkg * 4;
      float4 bv = *(const float4*)(bias + c0);
      uint2 q;
      q.x = pack2(accQ[nt][ct][0] + bv.x, accQ[nt][ct][1] + bv.y);
      q.y = pack2(accQ[nt][ct][2] + bv.z, accQ[nt][ct][3] + bv.w);
      *(uint2*)(Qb + (size_t)node * HD + c0) = q;
      Pb8[(size_t)node * 32 + (c0 >> 2)] =
          pk_fp8x4(accP[nt][ct][0], accP[nt][ct][1], accP[nt][ct][2], accP[nt][ct][3]);
    }
  }
}

// ---------------- gather (fp8 P) + layer epilogue, v4 ----------------
// one wave per node; lane = (eg = lane>>4: edge slot, cl = lane&15: uint2 col).
// v4: 16-edge leading batch (4 loads in flight) covers the common d~16 case;
// Q/Hres/snorm/inv_deg hoisted; indices preloaded coalesced + shfl broadcast.
__global__ __launch_bounds__(256) void k_gapply(const uint2* __restrict__ Pg,
                      const uint4* __restrict__ Qg, const uint4* __restrict__ Hres,
                      uint4* __restrict__ Og,
                      const int* __restrict__ row_start, const int* __restrict__ deg,
                      const int* __restrict__ esrc, const float* __restrict__ inv_deg,
                      const float* __restrict__ snorm,
                      const float* __restrict__ wcv, const int* __restrict__ gid,
                      const float* __restrict__ inv_gcnt, float* __restrict__ out,
                      int last) {
  int v = blockIdx.x * 4 + (threadIdx.x >> 6);
  int lane = threadIdx.x & 63;
  int eg = lane >> 4;                       // edge slot 0..3
  int cl = lane & 15;                       // uint2 col: fp8 cols 8cl..8cl+7
  int rs = __builtin_amdgcn_readfirstlane(row_start[v]);
  int d  = __builtin_amdgcn_readfirstlane(deg[v]);

  // ---- hoisted epilogue operands (latency hides under the gather) ----
  float id = inv_deg[v];
  float sn = snorm[v];
  uint4 q  = Qg[(size_t)v * 16 + cl];       // lanes 16+ replicate -> coalesced
  uint4 hr = Hres[(size_t)v * 16 + cl];

  // ---- coalesced index preload: all of this node's edges in one load ----
  int dcap = min(d, 64);
  int myidx = 0;
  if (lane < dcap) myidx = esrc[rs + lane];

  float a0 = 0.f, a1 = 0.f, a2 = 0.f, a3 = 0.f;
  float a4 = 0.f, a5 = 0.f, a6 = 0.f, a7 = 0.f;

#define ACCX(X)                                                             \
  { f32x2 p0 = __builtin_amdgcn_cvt_pk_f32_fp8((int)(X).x, false);          \
    f32x2 p1 = __builtin_amdgcn_cvt_pk_f32_fp8((int)(X).x, true);           \
    f32x2 p2 = __builtin_amdgcn_cvt_pk_f32_fp8((int)(X).y, false);          \
    f32x2 p3 = __builtin_amdgcn_cvt_pk_f32_fp8((int)(X).y, true);           \
    a0 += p0[0]; a1 += p0[1]; a2 += p1[0]; a3 += p1[1];                     \
    a4 += p2[0]; a5 += p2[1]; a6 += p3[0]; a7 += p3[1]; }

  int e = 0;
  for (; e + 16 <= dcap; e += 16) {         // 16 edges = 4 loads in flight
    int i0 = __shfl(myidx, e + eg, 64);
    int i1 = __shfl(myidx, e + 4 + eg, 64);
    int i2 = __shfl(myidx, e + 8 + eg, 64);
    int i3 = __shfl(myidx, e + 12 + eg, 64);
    uint2 x0 = Pg[(size_t)i0 * 16 + cl];
    uint2 x1 = Pg[(size_t)i1 * 16 + cl];
    uint2 x2 = Pg[(size_t)i2 * 16 + cl];
    uint2 x3 = Pg[(size_t)i3 * 16 + cl];
    ACCX(x0)
    ACCX(x1)
    ACCX(x2)
    ACCX(x3)
  }
  if (e + 8 <= dcap) {
    int i0 = __shfl(myidx, e + eg, 64);
    int i1 = __shfl(myidx, e + 4 + eg, 64);
    uint2 x0 = Pg[(size_t)i0 * 16 + cl];
    uint2 x1 = Pg[(size_t)i1 * 16 + cl];
    ACCX(x0)
    ACCX(x1)
    e += 8;
  }
  if (e + 4 <= dcap) {
    int i0 = __shfl(myidx, e + eg, 64);
    uint2 x = Pg[(size_t)i0 * 16 + cl];
    ACCX(x)
    e += 4;
  }
  if (e < dcap) {                           // masked tail (<4 edges)
    uint2 x = make_uint2(0u, 0u);
    if (e + eg < dcap) {
      int i0 = __shfl(myidx, e + eg, 64);
      x = Pg[(size_t)i0 * 16 + cl];
    }
    ACCX(x)
  }
  for (int ee = 64; ee < d; ee += 4) {      // d>64: essentially never (Poisson 16)
    uint2 x = make_uint2(0u, 0u);
    if (ee + eg < d) x = Pg[(size_t)esrc[rs + ee + eg] * 16 + cl];
    ACCX(x)
  }
#undef ACCX

  // reduce across the 4 edge slots
  a0 += __shfl_xor(a0, 16, 64);  a0 += __shfl_xor(a0, 32, 64);
  a1 += __shfl_xor(a1, 16, 64);  a1 += __shfl_xor(a1, 32, 64);
  a2 += __shfl_xor(a2, 16, 64);  a2 += __shfl_xor(a2, 32, 64);
  a3 += __shfl_xor(a3, 16, 64);  a3 += __shfl_xor(a3, 32, 64);
  a4 += __shfl_xor(a4, 16, 64);  a4 += __shfl_xor(a4, 32, 64);
  a5 += __shfl_xor(a5, 16, 64);  a5 += __shfl_xor(a5, 32, 64);
  a6 += __shfl_xor(a6, 16, 64);  a6 += __shfl_xor(a6, 32, 64);
  a7 += __shfl_xor(a7, 16, 64);  a7 += __shfl_xor(a7, 32, 64);

  if (eg == 0) {                            // lanes 0..15: full-row uint4 IO
    float o0 = fmaxf(blo(q.x) + a0 * id, 0.f) * sn + blo(hr.x);
    float o1 = fmaxf(bhi(q.x) + a1 * id, 0.f) * sn + bhi(hr.x);
    float o2 = fmaxf(blo(q.y) + a2 * id, 0.f) * sn + blo(hr.y);
    float o3 = fmaxf(bhi(q.y) + a3 * id, 0.f) * sn + bhi(hr.y);
    float o4 = fmaxf(blo(q.z) + a4 * id, 0.f) * sn + blo(hr.z);
    float o5 = fmaxf(bhi(q.z) + a5 * id, 0.f) * sn + bhi(hr.z);
    float o6 = fmaxf(blo(q.w) + a6 * id, 0.f) * sn + blo(hr.w);
    float o7 = fmaxf(bhi(q.w) + a7 * id, 0.f) * sn + bhi(hr.w);
    if (!last) {
      uint4 o;
      o.x = pack2(o0, o1);
      o.y = pack2(o2, o3);
      o.z = pack2(o4, o5);
      o.w = pack2(o6, o7);
      Og[(size_t)v * 16 + cl] = o;
    } else {
      float4 w0 = *(const float4*)(wcv + 8 * cl);
      float4 w1 = *(const float4*)(wcv + 8 * cl + 4);
      float p = o0 * w0.x + o1 * w0.y + o2 * w0.z + o3 * w0.w
              + o4 * w1.x + o5 * w1.y + o6 * w1.z + o7 * w1.w;
      p += __shfl_xor(p, 8, 64);
      p += __shfl_xor(p, 4, 64);
      p += __shfl_xor(p, 2, 64);
      p += __shfl_xor(p, 1, 64);
      if (cl == 0) {
        int g = gid[v];
        atomicAdd(&out[g], p * inv_gcnt[g]);
      }
    }
  }
}

// ---------------- launch ----------------
extern "C" void kernel_launch(void* const* d_in, const int* in_sizes, int n_in,
                              void* d_out, int out_size, void* d_ws, size_t ws_size,
                              hipStream_t stream) {
  const float* h      = (const float*)d_in[0];
  const float* snorm  = (const float*)d_in[1];
  const float* W_emb  = (const float*)d_in[2];
  const float* W_node = (const float*)d_in[3];
  const float* b_node = (const float*)d_in[4];
  const float* W_ro   = (const float*)d_in[5];
  const float* W_pred = (const float*)d_in[6];
  const float* b_pred = (const float*)d_in[7];
  const int*   src    = (const int*)d_in[8];
  const int*   dst    = (const int*)d_in[9];
  const int*   gid    = (const int*)d_in[10];
  float* out = (float*)d_out;

  char* ws = (char*)d_ws;
  unsigned short* Xb   = (unsigned short*)(ws + OFF_XB);
  unsigned short* Yb   = (unsigned short*)(ws + OFF_YB);
  uint*  Pb8      = (uint*)(ws + OFF_PB);
  int*   esrc     = (int*)(ws + OFF_ESRC);
  int*   deg      = (int*)(ws + OFF_DEG);
  int*   gcnt     = (int*)(ws + OFF_GCNT);
  int*   row_s    = (int*)(ws + OFF_ROW);
  float* inv_deg  = (float*)(ws + OFF_IDEG);
  float* inv_gcnt = (float*)(ws + OFF_IGC);
  float* wcv      = (float*)(ws + OFF_WC);
  unsigned short* Wnt = (unsigned short*)(ws + OFF_WNT);
  uint*  ebuf     = (uint*)(ws + OFF_EBUF);
  int*   gcur     = (int*)(ws + OFF_GCUR);
  unsigned short* Wet = (unsigned short*)(ws + OFF_WET);

  hipMemsetAsync(ws + OFF_GCNT, 0, (size_t)NG * 4, stream);

  k_ghist<<<NN / 256, 256, 0, stream>>>(gid, gcnt);
  k_prep<<<1 + NG / 256 + 512 + 16 + 1, 256, 0, stream>>>(
      gcur, gcnt, inv_gcnt, out, b_pred, W_node, Wnt, W_emb, Wet, W_ro, W_pred, wcv);
  k_bin<<<NE / 4096, 256, 0, stream>>>(src, dst, gcur, ebuf);
  k_csr<<<NB, 256, 0, stream>>>(gcur, ebuf, deg, row_s, inv_deg, esrc);

  k_embed<<<NN / 64, 256, 0, stream>>>(h, Wet, Xb);

  for (int l = 0; l < NL; l++) {
    unsigned short* hb = (l & 1) ? Yb : Xb;   // layer input
    unsigned short* qo = (l & 1) ? Xb : Yb;   // Q buffer, overwritten in-place by O
    k_pq<<<NN / 64, 256, 0, stream>>>(hb, Pb8, qo, Wnt + (size_t)l * HD * 256,
                                      b_node + (size_t)l * HD);
    k_gapply<<<NN / 4, 256, 0, stream>>>((const uint2*)Pb8, (const uint4*)qo,
                                         (const uint4*)hb, (uint4*)qo,
                                         row_s, deg, esrc, inv_deg, snorm,
                                         wcv, gid, inv_gcnt, out, (l == NL - 1) ? 1 : 0);
  }
}